// Round 5
// baseline (525.642 us; speedup 1.0000x reference)
//
#include <hip/hip_runtime.h>
#include <hip/hip_bf16.h>

// ---------------------------------------------------------------------------
// Fused + pipelined: per block (1 batch element, 4 waves):
//   15 iters x { conv of 2 frames (2 waves each) ; 2 GRU-encoder steps }
//   then autoregressive decoder (20 steps) + lin + cumsum.
// Rationale (R4 post-mortem): phase-sequential fusion left SIMDs idle during
// the GRU chains (VALUBusy 66%). Interleaving puts issue-dense conv work and
// latency-bound enc steps in the same instruction stream, so skewed blocks
// fill each other's stalls. Enc weights are NOT held across conv (R2 spill
// lesson): Wh reloaded per step from L2, Wi/biases staged in LDS.
// ---------------------------------------------------------------------------

#define B_    1024
#define L_    30
#define H_    64

__device__ __forceinline__ float sigmoid_f(float v) {
    return 1.f / (1.f + __expf(-v));
}
__device__ __forceinline__ float tanh_f(float v) {
    v = fminf(fmaxf(v, -15.f), 15.f);
    float e = __expf(2.f * v);
    return (e - 1.f) / (e + 1.f);
}
__device__ __forceinline__ void load4_lds(float* r, const float* p) {
    float2 a = *(const float2*)p;
    float2 b = *(const float2*)(p + 2);
    r[0] = a.x; r[1] = a.y; r[2] = b.x; r[3] = b.y;
}

__global__ __launch_bounds__(256, 4) void fused_pipe_kernel(
    const float* __restrict__ bbox,
    const float* __restrict__ head,
    const float* __restrict__ c1w, const float* __restrict__ c1b,
    const float* __restrict__ c2w, const float* __restrict__ c2b,
    const float* __restrict__ fcw, const float* __restrict__ fcb,
    const float* __restrict__ ewih, const float* __restrict__ ewhh,
    const float* __restrict__ ebih, const float* __restrict__ ebhh,
    const float* __restrict__ dwih, const float* __restrict__ dwhh,
    const float* __restrict__ dbih, const float* __restrict__ dbhh,
    const float* __restrict__ linw, const float* __restrict__ linb,
    float* __restrict__ out)
{
    const int b = blockIdx.x;
    const int tid = threadIdx.x;
    const int w = tid >> 6, lane = tid & 63;
    const int im  = w >> 1;   // which of the 2 per-iter images this wave works
    const int w01 = w & 1;    // which half of that image's work

    // LDS: 2 image scratchpads (img 1024 | p1 960 | p2 360; fc-red aliases img),
    //      enc_s[30][9], sp double-buffered partials, enc Wi/bias stage.
    __shared__ float s_scr[2][2344];
    __shared__ float enc_s[270];
    __shared__ float sp[2][4][3][64];
    __shared__ float wi_s[1728];     // ewih [192][9]
    __shared__ float bi_s[192];
    __shared__ float bh_s[192];
    // total 8606 floats = 34.4 KB -> 4 blocks/CU

    // stage enc input-side weights once (visible by first stage barrier)
    for (int idx = tid; idx < 1728; idx += 256) wi_s[idx] = ewih[idx];
    if (tid < 192) { bi_s[tid] = ebih[tid]; bh_s[tid] = ebhh[tid]; }

    float h = 0.f;   // GRU hidden, replicated across all 4 waves

    // one encoder GRU step (all 256 threads; 4-wave k-slice scheme)
    auto enc_step = [&](int t) {
        const int pb = t & 1;
        float Wh[3][16];
        #pragma unroll
        for (int g = 0; g < 3; ++g) {
            const float4* row = (const float4*)(ewhh + (size_t)(g * 64 + lane) * 64 + w * 16);
            #pragma unroll
            for (int k4 = 0; k4 < 4; ++k4) *(float4*)&Wh[g][4 * k4] = row[k4];
        }
        float pr = 0.f, pz = 0.f, pn = 0.f;
        #pragma unroll
        for (int k = 0; k < 16; ++k) {
            const float hk = __shfl(h, w * 16 + k);
            pr = fmaf(Wh[0][k], hk, pr);
            pz = fmaf(Wh[1][k], hk, pz);
            pn = fmaf(Wh[2][k], hk, pn);
        }
        sp[pb][w][0][lane] = pr;
        sp[pb][w][1][lane] = pz;
        sp[pb][w][2][lane] = pn;

        float Wi[3][9];
        #pragma unroll
        for (int g = 0; g < 3; ++g)
            #pragma unroll
            for (int k = 0; k < 9; ++k) Wi[g][k] = wi_s[(g * 64 + lane) * 9 + k];
        const float bi0 = bi_s[lane], bi1 = bi_s[64 + lane], bi2 = bi_s[128 + lane];
        const float bh0 = bh_s[lane], bh1 = bh_s[64 + lane], bh2 = bh_s[128 + lane];

        __syncthreads();   // sp + enc_s[t] visible

        float gr = bi0 + bh0, gz = bi1 + bh1, gni = bi2, gnh = bh2;
        #pragma unroll
        for (int k = 0; k < 9; ++k) {
            const float xk = enc_s[t * 9 + k];
            gr  = fmaf(Wi[0][k], xk, gr);
            gz  = fmaf(Wi[1][k], xk, gz);
            gni = fmaf(Wi[2][k], xk, gni);
        }
        #pragma unroll
        for (int ww = 0; ww < 4; ++ww) {
            gr  += sp[pb][ww][0][lane];
            gz  += sp[pb][ww][1][lane];
            gnh += sp[pb][ww][2][lane];
        }
        const float r = sigmoid_f(gr);
        const float z = sigmoid_f(gz);
        const float n = tanh_f(gni + r * gnh);
        h = (1.f - z) * n + z * h;
    };

    // =================== 15 iters: 2 frames conv + 2 enc steps =============
    for (int it = 0; it < 15; ++it) {
        const int f = 2 * it + im;
        float* simg = s_scr[im];
        float* sp1  = simg + 1024;
        float* sp2  = simg + 1984;

        // image load: 2 waves x 128 float4 per image
        {
            const float4* src = (const float4*)(head + ((size_t)b * 31 + f) * 1024);
            float4* dst = (float4*)simg;
            dst[w01 * 128 + lane]      = src[w01 * 128 + lane];
            dst[w01 * 128 + 64 + lane] = src[w01 * 128 + 64 + lane];
        }
        __syncthreads();

        // stage 1: conv1+relu+pool; lane=(c,px); wave-half splits py range
        if (lane < 60) {
            const int c = lane / 15, px = lane % 15, x0 = 2 * px;
            const int pybase = w01 * 8;
            const int pycnt  = w01 ? 7 : 8;       // wave-uniform
            float wg[9];
            #pragma unroll
            for (int k = 0; k < 9; ++k) wg[k] = c1w[c * 9 + k];
            const float bias = c1b[c];

            float r0[4], r1[4], r2[4], r3[4];
            load4_lds(r0, simg + (2 * pybase) * 32 + x0);
            load4_lds(r1, simg + (2 * pybase + 1) * 32 + x0);
            for (int pi = 0; pi < pycnt; ++pi) {
                const int py = pybase + pi;
                load4_lds(r2, simg + (2 * py + 2) * 32 + x0);
                load4_lds(r3, simg + (2 * py + 3) * 32 + x0);
                float a00 = bias, a01 = bias, a10 = bias, a11 = bias;
                #pragma unroll
                for (int kx = 0; kx < 3; ++kx) {
                    const float w0 = wg[kx], w1 = wg[3 + kx], w2 = wg[6 + kx];
                    a00 = fmaf(w0, r0[kx],     fmaf(w1, r1[kx],     fmaf(w2, r2[kx],     a00)));
                    a01 = fmaf(w0, r0[kx + 1], fmaf(w1, r1[kx + 1], fmaf(w2, r2[kx + 1], a01)));
                    a10 = fmaf(w0, r1[kx],     fmaf(w1, r2[kx],     fmaf(w2, r3[kx],     a10)));
                    a11 = fmaf(w0, r1[kx + 1], fmaf(w1, r2[kx + 1], fmaf(w2, r3[kx + 1], a11)));
                }
                a00 = fmaxf(a00, 0.f); a01 = fmaxf(a01, 0.f);
                a10 = fmaxf(a10, 0.f); a11 = fmaxf(a11, 0.f);
                sp1[c * 240 + py * 16 + px] = fmaxf(fmaxf(a00, a01), fmaxf(a10, a11));
                #pragma unroll
                for (int q = 0; q < 4; ++q) { r0[q] = r2[q]; r1[q] = r3[q]; }
            }
        }
        __syncthreads();

        // stage 2: conv2+relu+pool; lane=(c,px); wave-half splits py (3 each)
        if (lane < 60) {
            const int c = lane / 6, px = lane % 6, x0 = 2 * px;
            const int pybase = 3 * w01;
            float wg[4][9];
            #pragma unroll
            for (int ic = 0; ic < 4; ++ic)
                #pragma unroll
                for (int k = 0; k < 9; ++k) wg[ic][k] = c2w[(c * 4 + ic) * 9 + k];
            const float bias = c2b[c];

            float win[4][4][4];
            #pragma unroll
            for (int ic = 0; ic < 4; ++ic) {
                load4_lds(win[0][ic], sp1 + ic * 240 + (2 * pybase) * 16 + x0);
                load4_lds(win[1][ic], sp1 + ic * 240 + (2 * pybase + 1) * 16 + x0);
            }
            #pragma unroll
            for (int pi = 0; pi < 3; ++pi) {
                const int py = pybase + pi;
                #pragma unroll
                for (int ic = 0; ic < 4; ++ic) {
                    load4_lds(win[2][ic], sp1 + ic * 240 + (2 * py + 2) * 16 + x0);
                    load4_lds(win[3][ic], sp1 + ic * 240 + (2 * py + 3) * 16 + x0);
                }
                float a00 = bias, a01 = bias, a10 = bias, a11 = bias;
                #pragma unroll
                for (int ic = 0; ic < 4; ++ic) {
                    #pragma unroll
                    for (int kx = 0; kx < 3; ++kx) {
                        const float w0 = wg[ic][kx], w1 = wg[ic][3 + kx], w2 = wg[ic][6 + kx];
                        a00 = fmaf(w0, win[0][ic][kx],     fmaf(w1, win[1][ic][kx],     fmaf(w2, win[2][ic][kx],     a00)));
                        a01 = fmaf(w0, win[0][ic][kx + 1], fmaf(w1, win[1][ic][kx + 1], fmaf(w2, win[2][ic][kx + 1], a01)));
                        a10 = fmaf(w0, win[1][ic][kx],     fmaf(w1, win[2][ic][kx],     fmaf(w2, win[3][ic][kx],     a10)));
                        a11 = fmaf(w0, win[1][ic][kx + 1], fmaf(w1, win[2][ic][kx + 1], fmaf(w2, win[3][ic][kx + 1], a11)));
                    }
                }
                a00 = fmaxf(a00, 0.f); a01 = fmaxf(a01, 0.f);
                a10 = fmaxf(a10, 0.f); a11 = fmaxf(a11, 0.f);
                sp2[c * 36 + py * 6 + px] = fmaxf(fmaxf(a00, a01), fmaxf(a10, a11));
                #pragma unroll
                for (int ic = 0; ic < 4; ++ic)
                    #pragma unroll
                    for (int q = 0; q < 4; ++q) { win[0][ic][q] = win[2][ic][q]; win[1][ic][q] = win[3][ic][q]; }
            }
        }
        __syncthreads();

        // stage 3: fc partials; wave-half splits the k range (15 each)
        if (lane < 60) {
            const int o = lane / 12, i0 = lane % 12;
            const float* wrow = fcw + o * 360;
            const int kbase = w01 * 15;
            float acc = 0.f;
            #pragma unroll
            for (int kk = 0; kk < 15; ++kk) {
                const int i = i0 + 12 * (kbase + kk);
                acc = fmaf(wrow[i], sp2[i], acc);
            }
            simg[w01 * 60 + lane] = acc;     // red region aliases img (img dead)
        }
        __syncthreads();

        // finalize: emb -> enc_s[f][4..8], diffs -> enc_s[f][0..3]
        if (w01 == 0 && lane < 5) {
            float acc = fcb[lane];
            #pragma unroll
            for (int k = 0; k < 12; ++k)
                acc += simg[lane * 12 + k] + simg[60 + lane * 12 + k];
            enc_s[f * 9 + 4 + lane] = acc;
        } else if (w01 == 1 && lane < 4) {
            const float* bb = bbox + (size_t)b * 124 + f * 4;
            enc_s[f * 9 + lane] = bb[4 + lane] - bb[lane];
        }
        // (visibility of enc_s covered by the barrier inside enc_step)

        enc_step(2 * it);
        enc_step(2 * it + 1);
    }

    // =================== decoder: 20 steps + lin + cumsum ==================
    {
        float Wh[3][16];
        #pragma unroll
        for (int g = 0; g < 3; ++g) {
            const float4* row = (const float4*)(dwhh + (size_t)(g * 64 + lane) * 64 + w * 16);
            #pragma unroll
            for (int k4 = 0; k4 < 4; ++k4) *(float4*)&Wh[g][4 * k4] = row[k4];
        }
        float Wi[3][4];
        #pragma unroll
        for (int g = 0; g < 3; ++g) {
            const float* row = dwih + (g * 64 + lane) * 4;
            #pragma unroll
            for (int k = 0; k < 4; ++k) Wi[g][k] = row[k];
        }
        const float bi0 = dbih[lane], bi1 = dbih[64 + lane], bi2 = dbih[128 + lane];
        const float bh0 = dbhh[lane], bh1 = dbhh[64 + lane], bh2 = dbhh[128 + lane];
        const float lw0 = linw[lane], lw1 = linw[64 + lane], lw2 = linw[128 + lane], lw3 = linw[192 + lane];
        const float lb0 = linb[0], lb1 = linb[1], lb2 = linb[2], lb3 = linb[3];

        const float* bb = bbox + (size_t)b * 124;
        float px0 = bb[120] - bb[116];
        float px1 = bb[121] - bb[117];
        float px2 = bb[122] - bb[118];
        float px3 = bb[123] - bb[119];
        const float of0 = bb[120], of1 = bb[121], of2 = bb[122], of3 = bb[123];
        float cs0 = 0.f, cs1 = 0.f, cs2 = 0.f, cs3 = 0.f;
        float4* outp = (float4*)(out + (size_t)b * 80);

        for (int t = 0; t < 20; ++t) {
            const int pb = t & 1;
            float pr = 0.f, pz = 0.f, pn = 0.f;
            #pragma unroll
            for (int k = 0; k < 16; ++k) {
                const float hk = __shfl(h, w * 16 + k);
                pr = fmaf(Wh[0][k], hk, pr);
                pz = fmaf(Wh[1][k], hk, pz);
                pn = fmaf(Wh[2][k], hk, pn);
            }
            sp[pb][w][0][lane] = pr;
            sp[pb][w][1][lane] = pz;
            sp[pb][w][2][lane] = pn;

            float gr = bi0 + bh0, gz = bi1 + bh1, gni = bi2, gnh = bh2;
            gr  = fmaf(Wi[0][0], px0, fmaf(Wi[0][1], px1, fmaf(Wi[0][2], px2, fmaf(Wi[0][3], px3, gr))));
            gz  = fmaf(Wi[1][0], px0, fmaf(Wi[1][1], px1, fmaf(Wi[1][2], px2, fmaf(Wi[1][3], px3, gz))));
            gni = fmaf(Wi[2][0], px0, fmaf(Wi[2][1], px1, fmaf(Wi[2][2], px2, fmaf(Wi[2][3], px3, gni))));

            __syncthreads();
            #pragma unroll
            for (int ww = 0; ww < 4; ++ww) {
                gr  += sp[pb][ww][0][lane];
                gz  += sp[pb][ww][1][lane];
                gnh += sp[pb][ww][2][lane];
            }
            const float r = sigmoid_f(gr);
            const float z = sigmoid_f(gz);
            const float n = tanh_f(gni + r * gnh);
            h = (1.f - z) * n + z * h;

            float v0 = lw0 * h, v1 = lw1 * h, v2 = lw2 * h, v3 = lw3 * h;
            #pragma unroll
            for (int s = 32; s > 0; s >>= 1) {
                v0 += __shfl_xor(v0, s);
                v1 += __shfl_xor(v1, s);
                v2 += __shfl_xor(v2, s);
                v3 += __shfl_xor(v3, s);
            }
            px0 = v0 + lb0 + px0;
            px1 = v1 + lb1 + px1;
            px2 = v2 + lb2 + px2;
            px3 = v3 + lb3 + px3;
            cs0 += px0; cs1 += px1; cs2 += px2; cs3 += px3;
            if (tid == 0) outp[t] = make_float4(cs0 + of0, cs1 + of1, cs2 + of2, cs3 + of3);
        }
    }
}

// ---------------------------------------------------------------------------
extern "C" void kernel_launch(void* const* d_in, const int* in_sizes, int n_in,
                              void* d_out, int out_size, void* d_ws, size_t ws_size,
                              hipStream_t stream) {
    (void)in_sizes; (void)n_in; (void)out_size; (void)d_ws; (void)ws_size;
    const float* bbox = (const float*)d_in[0];
    const float* head = (const float*)d_in[1];
    const float* c1w  = (const float*)d_in[2];
    const float* c1b  = (const float*)d_in[3];
    const float* c2w  = (const float*)d_in[4];
    const float* c2b  = (const float*)d_in[5];
    const float* fcw  = (const float*)d_in[6];
    const float* fcb  = (const float*)d_in[7];
    const float* ewih = (const float*)d_in[8];
    const float* ewhh = (const float*)d_in[9];
    const float* ebih = (const float*)d_in[10];
    const float* ebhh = (const float*)d_in[11];
    const float* dwih = (const float*)d_in[12];
    const float* dwhh = (const float*)d_in[13];
    const float* dbih = (const float*)d_in[14];
    const float* dbhh = (const float*)d_in[15];
    const float* linw = (const float*)d_in[16];
    const float* linb = (const float*)d_in[17];
    float* out = (float*)d_out;

    fused_pipe_kernel<<<B_, 256, 0, stream>>>(bbox, head, c1w, c1b, c2w, c2b,
                                              fcw, fcb, ewih, ewhh, ebih, ebhh,
                                              dwih, dwhh, dbih, dbhh, linw, linb,
                                              out);
}

// Round 6
// 346.033 us; speedup vs baseline: 1.5191x; 1.5191x over previous
//
#include <hip/hip_runtime.h>
#include <hip/hip_bf16.h>

// ---------------------------------------------------------------------------
// Fused, sequential phases (R4 structure), GRU phases rebuilt per R5 findings:
//  - weight broadcast via v_readlane (scalar pipe) instead of __shfl (LDS pipe)
//  - gate-partial exchange packed into float4 LDS ops (1 write + 4 reads)
//  - enc_s padded to stride 12 -> x loads are 3x ds_read_b128
//  - Wh/Wi loaded ONCE before each GRU loop; launch_bounds(256,4) caps VGPR at
//    128 which fits the ~116-reg live set so the compiler can hold them.
// B=1024 blocks x 256 threads (4 waves), 4 blocks/CU (LDS 39.97 KB).
// ---------------------------------------------------------------------------

#define B_    1024
#define L_    30
#define H_    64

__device__ __forceinline__ float sigmoid_f(float v) {
    return 1.f / (1.f + __expf(-v));
}
__device__ __forceinline__ float tanh_f(float v) {
    v = fminf(fmaxf(v, -15.f), 15.f);
    float e = __expf(2.f * v);
    return (e - 1.f) / (e + 1.f);
}
__device__ __forceinline__ float bcast(float v, int sl) {
    // sl is wave-uniform (SGPR) -> v_readlane_b32: scalar-pipe broadcast
    return __int_as_float(__builtin_amdgcn_readlane(__float_as_int(v), sl));
}
__device__ __forceinline__ void load4_lds(float* r, const float* p) {
    float2 a = *(const float2*)p;
    float2 b = *(const float2*)(p + 2);
    r[0] = a.x; r[1] = a.y; r[2] = b.x; r[3] = b.y;
}

__global__ __launch_bounds__(256, 4) void fused_all_kernel(
    const float* __restrict__ bbox,
    const float* __restrict__ head,
    const float* __restrict__ c1w, const float* __restrict__ c1b,
    const float* __restrict__ c2w, const float* __restrict__ c2b,
    const float* __restrict__ fcw, const float* __restrict__ fcb,
    const float* __restrict__ ewih, const float* __restrict__ ewhh,
    const float* __restrict__ ebih, const float* __restrict__ ebhh,
    const float* __restrict__ dwih, const float* __restrict__ dwhh,
    const float* __restrict__ dbih, const float* __restrict__ dbhh,
    const float* __restrict__ linw, const float* __restrict__ linb,
    float* __restrict__ out)
{
    const int b = blockIdx.x;
    const int tid = threadIdx.x;
    const int w = tid >> 6, lane = tid & 63;

    // [0..9631] 4x per-wave conv scratch (img 1024 | p1 960 | p2 360 | red 64)
    // [9632..9991] enc_s[30][12] (stride-12 pad for b128 x-loads)
    // sp4[2][4][64][4] (2048 floats) aliases conv scratch after conv phase.
    alignas(16) __shared__ float smem[9992];
    float* enc_s = smem + 9632;
    float* sp4   = smem;
    float* wb    = smem + w * 2408;
    float* s_img = wb;
    float* s_p1  = wb + 1024;
    float* s_p2  = wb + 1984;
    float* s_red = wb + 2344;

    // =================== conv phase: 30 images over 8 iters ================
    for (int it = 0; it < 8; ++it) {
        const int l = it * 4 + w;
        const bool act = (l < L_);

        if (act) {
            const float4* src = (const float4*)(head + ((size_t)b * 31 + (size_t)l) * 1024);
            float4* dst = (float4*)s_img;
            #pragma unroll
            for (int i = 0; i < 4; ++i) dst[lane + 64 * i] = src[lane + 64 * i];
        }
        __syncthreads();

        // stage 1: conv1 + relu + pool; lane = (c, px), rolling 4-row window
        if (act && lane < 60) {
            const int c = lane / 15, px = lane % 15;
            const int x0 = 2 * px;
            float wg[9];
            #pragma unroll
            for (int k = 0; k < 9; ++k) wg[k] = c1w[c * 9 + k];
            const float bias = c1b[c];

            float r0[4], r1[4], r2[4], r3[4];
            load4_lds(r0, s_img + 0 * 32 + x0);
            load4_lds(r1, s_img + 1 * 32 + x0);
            #pragma unroll
            for (int py = 0; py < 15; ++py) {
                load4_lds(r2, s_img + (2 * py + 2) * 32 + x0);
                load4_lds(r3, s_img + (2 * py + 3) * 32 + x0);
                float a00 = bias, a01 = bias, a10 = bias, a11 = bias;
                #pragma unroll
                for (int kx = 0; kx < 3; ++kx) {
                    const float w0 = wg[kx], w1 = wg[3 + kx], w2 = wg[6 + kx];
                    a00 = fmaf(w0, r0[kx],     fmaf(w1, r1[kx],     fmaf(w2, r2[kx],     a00)));
                    a01 = fmaf(w0, r0[kx + 1], fmaf(w1, r1[kx + 1], fmaf(w2, r2[kx + 1], a01)));
                    a10 = fmaf(w0, r1[kx],     fmaf(w1, r2[kx],     fmaf(w2, r3[kx],     a10)));
                    a11 = fmaf(w0, r1[kx + 1], fmaf(w1, r2[kx + 1], fmaf(w2, r3[kx + 1], a11)));
                }
                a00 = fmaxf(a00, 0.f); a01 = fmaxf(a01, 0.f);
                a10 = fmaxf(a10, 0.f); a11 = fmaxf(a11, 0.f);
                s_p1[c * 240 + py * 16 + px] = fmaxf(fmaxf(a00, a01), fmaxf(a10, a11));
                #pragma unroll
                for (int q = 0; q < 4; ++q) { r0[q] = r2[q]; r1[q] = r3[q]; }
            }
        }
        __syncthreads();

        // stage 2: conv2 + relu + pool; lane = (c, px), rolling window
        if (act && lane < 60) {
            const int c = lane / 6, px = lane % 6;
            const int x0 = 2 * px;
            float wg[4][9];
            #pragma unroll
            for (int ic = 0; ic < 4; ++ic)
                #pragma unroll
                for (int k = 0; k < 9; ++k) wg[ic][k] = c2w[(c * 4 + ic) * 9 + k];
            const float bias = c2b[c];

            float win[4][4][4];
            #pragma unroll
            for (int ic = 0; ic < 4; ++ic) {
                load4_lds(win[0][ic], s_p1 + ic * 240 + 0 * 16 + x0);
                load4_lds(win[1][ic], s_p1 + ic * 240 + 1 * 16 + x0);
            }
            #pragma unroll
            for (int py = 0; py < 6; ++py) {
                #pragma unroll
                for (int ic = 0; ic < 4; ++ic) {
                    load4_lds(win[2][ic], s_p1 + ic * 240 + (2 * py + 2) * 16 + x0);
                    load4_lds(win[3][ic], s_p1 + ic * 240 + (2 * py + 3) * 16 + x0);
                }
                float a00 = bias, a01 = bias, a10 = bias, a11 = bias;
                #pragma unroll
                for (int ic = 0; ic < 4; ++ic) {
                    #pragma unroll
                    for (int kx = 0; kx < 3; ++kx) {
                        const float w0 = wg[ic][kx], w1 = wg[ic][3 + kx], w2 = wg[ic][6 + kx];
                        a00 = fmaf(w0, win[0][ic][kx],     fmaf(w1, win[1][ic][kx],     fmaf(w2, win[2][ic][kx],     a00)));
                        a01 = fmaf(w0, win[0][ic][kx + 1], fmaf(w1, win[1][ic][kx + 1], fmaf(w2, win[2][ic][kx + 1], a01)));
                        a10 = fmaf(w0, win[1][ic][kx],     fmaf(w1, win[2][ic][kx],     fmaf(w2, win[3][ic][kx],     a10)));
                        a11 = fmaf(w0, win[1][ic][kx + 1], fmaf(w1, win[2][ic][kx + 1], fmaf(w2, win[3][ic][kx + 1], a11)));
                    }
                }
                a00 = fmaxf(a00, 0.f); a01 = fmaxf(a01, 0.f);
                a10 = fmaxf(a10, 0.f); a11 = fmaxf(a11, 0.f);
                s_p2[c * 36 + py * 6 + px] = fmaxf(fmaxf(a00, a01), fmaxf(a10, a11));
                #pragma unroll
                for (int ic = 0; ic < 4; ++ic)
                    #pragma unroll
                    for (int q = 0; q < 4; ++q) { win[0][ic][q] = win[2][ic][q]; win[1][ic][q] = win[3][ic][q]; }
            }
        }
        __syncthreads();

        // stage 3: fc 360->5 partials
        if (act && lane < 60) {
            const int o = lane / 12, i0 = lane % 12;
            const float* wrow = fcw + o * 360;
            float acc = 0.f;
            #pragma unroll
            for (int k = 0; k < 30; ++k) {
                const int i = i0 + 12 * k;
                acc = fmaf(wrow[i], s_p2[i], acc);
            }
            s_red[lane] = acc;
        }
        __syncthreads();

        if (act) {
            if (lane < 5) {
                float acc = fcb[lane];
                #pragma unroll
                for (int k = 0; k < 12; ++k) acc += s_red[lane * 12 + k];
                enc_s[l * 12 + 4 + lane] = acc;
            } else if (lane >= 8 && lane < 12) {
                const int d = lane - 8;
                const float* bb = bbox + (size_t)b * 124 + (size_t)l * 4;
                enc_s[l * 12 + d] = bb[4 + d] - bb[d];
            }
        }
    }
    __syncthreads();   // enc_s complete; conv scratch free -> sp4

    const int j = lane;
    const int lane_base = ((__builtin_amdgcn_readfirstlane(tid)) >> 6) << 4; // w*16, SGPR
    float h = 0.f;

    // =================== GRU encoder: 30 steps =============================
    {
        float Wh[3][16];
        #pragma unroll
        for (int g = 0; g < 3; ++g) {
            const float4* row = (const float4*)(ewhh + (size_t)(g * 64 + j) * 64 + w * 16);
            #pragma unroll
            for (int k4 = 0; k4 < 4; ++k4) *(float4*)&Wh[g][4 * k4] = row[k4];
        }
        float Wi[3][9];
        #pragma unroll
        for (int g = 0; g < 3; ++g) {
            const float* row = ewih + (g * 64 + j) * 9;
            #pragma unroll
            for (int k = 0; k < 9; ++k) Wi[g][k] = row[k];
        }
        const float bi0 = ebih[j], bi1 = ebih[64 + j], bi2 = ebih[128 + j];
        const float bh0 = ebhh[j], bh1 = ebhh[64 + j], bh2 = ebhh[128 + j];

        #pragma unroll 1
        for (int t = 0; t < L_; ++t) {
            const int pb = t & 1;
            float pr = 0.f, pz = 0.f, pn = 0.f;
            #pragma unroll
            for (int k = 0; k < 16; ++k) {
                const float hk = bcast(h, lane_base + k);
                pr = fmaf(Wh[0][k], hk, pr);
                pz = fmaf(Wh[1][k], hk, pz);
                pn = fmaf(Wh[2][k], hk, pn);
            }
            *(float4*)&sp4[((pb * 4 + w) * 64 + j) * 4] = make_float4(pr, pz, pn, 0.f);

            const float4 xa = *(const float4*)&enc_s[t * 12];
            const float4 xb = *(const float4*)&enc_s[t * 12 + 4];
            const float  x8 = enc_s[t * 12 + 8];
            float gr = bi0 + bh0, gz = bi1 + bh1, gni = bi2, gnh = bh2;
            gr  = fmaf(Wi[0][0], xa.x, fmaf(Wi[0][1], xa.y, fmaf(Wi[0][2], xa.z, fmaf(Wi[0][3], xa.w, gr))));
            gz  = fmaf(Wi[1][0], xa.x, fmaf(Wi[1][1], xa.y, fmaf(Wi[1][2], xa.z, fmaf(Wi[1][3], xa.w, gz))));
            gni = fmaf(Wi[2][0], xa.x, fmaf(Wi[2][1], xa.y, fmaf(Wi[2][2], xa.z, fmaf(Wi[2][3], xa.w, gni))));
            gr  = fmaf(Wi[0][4], xb.x, fmaf(Wi[0][5], xb.y, fmaf(Wi[0][6], xb.z, fmaf(Wi[0][7], xb.w, gr))));
            gz  = fmaf(Wi[1][4], xb.x, fmaf(Wi[1][5], xb.y, fmaf(Wi[1][6], xb.z, fmaf(Wi[1][7], xb.w, gz))));
            gni = fmaf(Wi[2][4], xb.x, fmaf(Wi[2][5], xb.y, fmaf(Wi[2][6], xb.z, fmaf(Wi[2][7], xb.w, gni))));
            gr  = fmaf(Wi[0][8], x8, gr);
            gz  = fmaf(Wi[1][8], x8, gz);
            gni = fmaf(Wi[2][8], x8, gni);

            __syncthreads();
            #pragma unroll
            for (int ww = 0; ww < 4; ++ww) {
                const float4 p = *(const float4*)&sp4[((pb * 4 + ww) * 64 + j) * 4];
                gr += p.x; gz += p.y; gnh += p.z;
            }
            const float r = sigmoid_f(gr);
            const float z = sigmoid_f(gz);
            const float n = tanh_f(gni + r * gnh);
            h = (1.f - z) * n + z * h;   // h replicated in all 4 waves
        }
    }

    // =================== decoder: 20 steps + lin + cumsum ==================
    {
        float Wh[3][16];
        #pragma unroll
        for (int g = 0; g < 3; ++g) {
            const float4* row = (const float4*)(dwhh + (size_t)(g * 64 + j) * 64 + w * 16);
            #pragma unroll
            for (int k4 = 0; k4 < 4; ++k4) *(float4*)&Wh[g][4 * k4] = row[k4];
        }
        float Wi[3][4];
        #pragma unroll
        for (int g = 0; g < 3; ++g) {
            const float* row = dwih + (g * 64 + j) * 4;
            #pragma unroll
            for (int k = 0; k < 4; ++k) Wi[g][k] = row[k];
        }
        const float bi0 = dbih[j], bi1 = dbih[64 + j], bi2 = dbih[128 + j];
        const float bh0 = dbhh[j], bh1 = dbhh[64 + j], bh2 = dbhh[128 + j];
        const float lw0 = linw[j], lw1 = linw[64 + j], lw2 = linw[128 + j], lw3 = linw[192 + j];
        const float lb0 = linb[0], lb1 = linb[1], lb2 = linb[2], lb3 = linb[3];

        const float* bb = bbox + (size_t)b * 124;
        float px0 = bb[120] - bb[116];
        float px1 = bb[121] - bb[117];
        float px2 = bb[122] - bb[118];
        float px3 = bb[123] - bb[119];
        const float of0 = bb[120], of1 = bb[121], of2 = bb[122], of3 = bb[123];
        float cs0 = 0.f, cs1 = 0.f, cs2 = 0.f, cs3 = 0.f;
        float4* outp = (float4*)(out + (size_t)b * 80);

        #pragma unroll 1
        for (int t = 0; t < 20; ++t) {
            const int pb = t & 1;
            float pr = 0.f, pz = 0.f, pn = 0.f;
            #pragma unroll
            for (int k = 0; k < 16; ++k) {
                const float hk = bcast(h, lane_base + k);
                pr = fmaf(Wh[0][k], hk, pr);
                pz = fmaf(Wh[1][k], hk, pz);
                pn = fmaf(Wh[2][k], hk, pn);
            }
            *(float4*)&sp4[((pb * 4 + w) * 64 + j) * 4] = make_float4(pr, pz, pn, 0.f);

            float gr = bi0 + bh0, gz = bi1 + bh1, gni = bi2, gnh = bh2;
            gr  = fmaf(Wi[0][0], px0, fmaf(Wi[0][1], px1, fmaf(Wi[0][2], px2, fmaf(Wi[0][3], px3, gr))));
            gz  = fmaf(Wi[1][0], px0, fmaf(Wi[1][1], px1, fmaf(Wi[1][2], px2, fmaf(Wi[1][3], px3, gz))));
            gni = fmaf(Wi[2][0], px0, fmaf(Wi[2][1], px1, fmaf(Wi[2][2], px2, fmaf(Wi[2][3], px3, gni))));

            __syncthreads();
            #pragma unroll
            for (int ww = 0; ww < 4; ++ww) {
                const float4 p = *(const float4*)&sp4[((pb * 4 + ww) * 64 + j) * 4];
                gr += p.x; gz += p.y; gnh += p.z;
            }
            const float r = sigmoid_f(gr);
            const float z = sigmoid_f(gz);
            const float n = tanh_f(gni + r * gnh);
            h = (1.f - z) * n + z * h;

            float v0 = lw0 * h, v1 = lw1 * h, v2 = lw2 * h, v3 = lw3 * h;
            #pragma unroll
            for (int s = 32; s > 0; s >>= 1) {
                v0 += __shfl_xor(v0, s);
                v1 += __shfl_xor(v1, s);
                v2 += __shfl_xor(v2, s);
                v3 += __shfl_xor(v3, s);
            }
            px0 = v0 + lb0 + px0;
            px1 = v1 + lb1 + px1;
            px2 = v2 + lb2 + px2;
            px3 = v3 + lb3 + px3;
            cs0 += px0; cs1 += px1; cs2 += px2; cs3 += px3;
            if (tid == 0) outp[t] = make_float4(cs0 + of0, cs1 + of1, cs2 + of2, cs3 + of3);
        }
    }
}

// ---------------------------------------------------------------------------
extern "C" void kernel_launch(void* const* d_in, const int* in_sizes, int n_in,
                              void* d_out, int out_size, void* d_ws, size_t ws_size,
                              hipStream_t stream) {
    (void)in_sizes; (void)n_in; (void)out_size; (void)d_ws; (void)ws_size;
    const float* bbox = (const float*)d_in[0];
    const float* head = (const float*)d_in[1];
    const float* c1w  = (const float*)d_in[2];
    const float* c1b  = (const float*)d_in[3];
    const float* c2w  = (const float*)d_in[4];
    const float* c2b  = (const float*)d_in[5];
    const float* fcw  = (const float*)d_in[6];
    const float* fcb  = (const float*)d_in[7];
    const float* ewih = (const float*)d_in[8];
    const float* ewhh = (const float*)d_in[9];
    const float* ebih = (const float*)d_in[10];
    const float* ebhh = (const float*)d_in[11];
    const float* dwih = (const float*)d_in[12];
    const float* dwhh = (const float*)d_in[13];
    const float* dbih = (const float*)d_in[14];
    const float* dbhh = (const float*)d_in[15];
    const float* linw = (const float*)d_in[16];
    const float* linb = (const float*)d_in[17];
    float* out = (float*)d_out;

    fused_all_kernel<<<B_, 256, 0, stream>>>(bbox, head, c1w, c1b, c2w, c2b,
                                             fcw, fcb, ewih, ewhh, ebih, ebhh,
                                             dwih, dwhh, dbih, dbhh, linw, linb,
                                             out);
}

// Round 7
// 320.384 us; speedup vs baseline: 1.6407x; 1.0801x over previous
//
#include <hip/hip_runtime.h>
#include <hip/hip_bf16.h>

// ---------------------------------------------------------------------------
// Split pipeline (R6 post-mortem: fused GRU was L2-BW-bound on per-step
// weight re-fetch because launch_bounds(256,4) forbade holding weights):
//   K1 conv_embed : R1 kernel, measured 90us, VALU-issue-bound.
//   K2 gru_encdec : ONE WAVE per batch element, enc+dec fused, weights truly
//                   register-resident under __launch_bounds__(64,1) (VGPR cap
//                   512; live set ~260). h broadcast via literal v_readlane;
//                   x broadcast via same-address LDS reads (free).
// ---------------------------------------------------------------------------

#define B_    1024
#define L_    30
#define H_    64

__device__ __forceinline__ float sigmoid_f(float v) {
    return 1.f / (1.f + __expf(-v));
}
__device__ __forceinline__ float tanh_f(float v) {
    v = fminf(fmaxf(v, -15.f), 15.f);
    float e = __expf(2.f * v);
    return (e - 1.f) / (e + 1.f);
}
__device__ __forceinline__ float bcast(float v, int lane) {
    // lane is a literal at every call site -> v_readlane_b32 imm
    return __int_as_float(__builtin_amdgcn_readlane(__float_as_int(v), lane));
}
__device__ __forceinline__ void load4_lds(float* r, const float* p) {
    float2 a = *(const float2*)p;
    float2 b = *(const float2*)(p + 2);
    r[0] = a.x; r[1] = a.y; r[2] = b.x; r[3] = b.y;
}

// ---------------------------------------------------------------------------
// Kernel A (R1, measured 90us): per-image conv encoder + fc.
// ---------------------------------------------------------------------------
__global__ __launch_bounds__(64) void conv_embed_kernel(
    const float* __restrict__ bbox,
    const float* __restrict__ head,
    const float* __restrict__ c1w, const float* __restrict__ c1b,
    const float* __restrict__ c2w, const float* __restrict__ c2b,
    const float* __restrict__ fcw, const float* __restrict__ fcb,
    float* __restrict__ enc_in)
{
    const int img = blockIdx.x;          // 0..30719
    const int b = img / L_;
    const int l = img % L_;
    const int tid = threadIdx.x;

    __shared__ float s_img[32 * 32];
    __shared__ float s_p1[4 * 15 * 16];
    __shared__ float s_p2[360];
    __shared__ float s_red[60];

    {
        const float4* src = (const float4*)(head + ((size_t)b * 31 + (size_t)l) * 1024);
        float4* dst = (float4*)s_img;
        #pragma unroll
        for (int i = 0; i < 4; ++i) dst[tid + 64 * i] = src[tid + 64 * i];
    }
    __syncthreads();

    if (tid < 60) {
        const int c = tid / 15, px = tid % 15;
        const int x0 = 2 * px;
        float w[9];
        #pragma unroll
        for (int k = 0; k < 9; ++k) w[k] = c1w[c * 9 + k];
        const float bias = c1b[c];

        float r0[4], r1[4], r2[4], r3[4];
        load4_lds(r0, s_img + 0 * 32 + x0);
        load4_lds(r1, s_img + 1 * 32 + x0);
        #pragma unroll
        for (int py = 0; py < 15; ++py) {
            load4_lds(r2, s_img + (2 * py + 2) * 32 + x0);
            load4_lds(r3, s_img + (2 * py + 3) * 32 + x0);
            float a00 = bias, a01 = bias, a10 = bias, a11 = bias;
            #pragma unroll
            for (int kx = 0; kx < 3; ++kx) {
                const float w0 = w[kx], w1 = w[3 + kx], w2 = w[6 + kx];
                a00 = fmaf(w0, r0[kx],     fmaf(w1, r1[kx],     fmaf(w2, r2[kx],     a00)));
                a01 = fmaf(w0, r0[kx + 1], fmaf(w1, r1[kx + 1], fmaf(w2, r2[kx + 1], a01)));
                a10 = fmaf(w0, r1[kx],     fmaf(w1, r2[kx],     fmaf(w2, r3[kx],     a10)));
                a11 = fmaf(w0, r1[kx + 1], fmaf(w1, r2[kx + 1], fmaf(w2, r3[kx + 1], a11)));
            }
            a00 = fmaxf(a00, 0.f); a01 = fmaxf(a01, 0.f);
            a10 = fmaxf(a10, 0.f); a11 = fmaxf(a11, 0.f);
            s_p1[c * 240 + py * 16 + px] = fmaxf(fmaxf(a00, a01), fmaxf(a10, a11));
            #pragma unroll
            for (int q = 0; q < 4; ++q) { r0[q] = r2[q]; r1[q] = r3[q]; }
        }
    }
    __syncthreads();

    if (tid < 60) {
        const int c = tid / 6, px = tid % 6;
        const int x0 = 2 * px;
        float w[4][9];
        #pragma unroll
        for (int ic = 0; ic < 4; ++ic)
            #pragma unroll
            for (int k = 0; k < 9; ++k) w[ic][k] = c2w[(c * 4 + ic) * 9 + k];
        const float bias = c2b[c];

        float win[4][4][4];
        #pragma unroll
        for (int ic = 0; ic < 4; ++ic) {
            load4_lds(win[0][ic], s_p1 + ic * 240 + 0 * 16 + x0);
            load4_lds(win[1][ic], s_p1 + ic * 240 + 1 * 16 + x0);
        }
        #pragma unroll
        for (int py = 0; py < 6; ++py) {
            #pragma unroll
            for (int ic = 0; ic < 4; ++ic) {
                load4_lds(win[2][ic], s_p1 + ic * 240 + (2 * py + 2) * 16 + x0);
                load4_lds(win[3][ic], s_p1 + ic * 240 + (2 * py + 3) * 16 + x0);
            }
            float a00 = bias, a01 = bias, a10 = bias, a11 = bias;
            #pragma unroll
            for (int ic = 0; ic < 4; ++ic) {
                #pragma unroll
                for (int kx = 0; kx < 3; ++kx) {
                    const float w0 = w[ic][kx], w1 = w[ic][3 + kx], w2 = w[ic][6 + kx];
                    a00 = fmaf(w0, win[0][ic][kx],     fmaf(w1, win[1][ic][kx],     fmaf(w2, win[2][ic][kx],     a00)));
                    a01 = fmaf(w0, win[0][ic][kx + 1], fmaf(w1, win[1][ic][kx + 1], fmaf(w2, win[2][ic][kx + 1], a01)));
                    a10 = fmaf(w0, win[1][ic][kx],     fmaf(w1, win[2][ic][kx],     fmaf(w2, win[3][ic][kx],     a10)));
                    a11 = fmaf(w0, win[1][ic][kx + 1], fmaf(w1, win[2][ic][kx + 1], fmaf(w2, win[3][ic][kx + 1], a11)));
                }
            }
            a00 = fmaxf(a00, 0.f); a01 = fmaxf(a01, 0.f);
            a10 = fmaxf(a10, 0.f); a11 = fmaxf(a11, 0.f);
            s_p2[c * 36 + py * 6 + px] = fmaxf(fmaxf(a00, a01), fmaxf(a10, a11));
            #pragma unroll
            for (int ic = 0; ic < 4; ++ic)
                #pragma unroll
                for (int q = 0; q < 4; ++q) { win[0][ic][q] = win[2][ic][q]; win[1][ic][q] = win[3][ic][q]; }
        }
    }
    __syncthreads();

    if (tid < 60) {
        const int o = tid / 12, i0 = tid % 12;
        const float* wrow = fcw + o * 360;
        float acc = 0.f;
        #pragma unroll
        for (int k = 0; k < 30; ++k) {
            const int i = i0 + 12 * k;
            acc = fmaf(wrow[i], s_p2[i], acc);
        }
        s_red[tid] = acc;
    }
    __syncthreads();

    float* dst = enc_in + ((size_t)b * L_ + l) * 9;
    if (tid < 5) {
        float acc = fcb[tid];
        #pragma unroll
        for (int k = 0; k < 12; ++k) acc += s_red[tid * 12 + k];
        dst[4 + tid] = acc;
    } else if (tid >= 8 && tid < 12) {
        const int d = tid - 8;
        const float* bb = bbox + (size_t)b * 124 + (size_t)l * 4;
        dst[d] = bb[4 + d] - bb[d];
    }
}

// ---------------------------------------------------------------------------
// Kernel B: encoder + decoder, ONE WAVE per batch element.
// launch_bounds(64,1) -> VGPR cap 512; Wh[3][64] (192 regs) held in registers.
// ---------------------------------------------------------------------------
__global__ __launch_bounds__(64, 1) void gru_encdec_kernel(
    const float* __restrict__ bbox,     // [1024][31][4]
    const float* __restrict__ enc_in,   // [1024][30][9]
    const float* __restrict__ ewih, const float* __restrict__ ewhh,
    const float* __restrict__ ebih, const float* __restrict__ ebhh,
    const float* __restrict__ dwih, const float* __restrict__ dwhh,
    const float* __restrict__ dbih, const float* __restrict__ dbhh,
    const float* __restrict__ linw, const float* __restrict__ linb,
    float* __restrict__ out)            // [1024][20][4]
{
    const int b = blockIdx.x;
    const int j = threadIdx.x;          // 0..63

    __shared__ float xs[272];           // enc_in[b] staged: 30*9 floats
    for (int i = j; i < 270; i += 64) xs[i] = enc_in[(size_t)b * 270 + i];

    float h = 0.f;

    // =================== encoder: 30 steps =================================
    {
        float Wh[3][64];
        #pragma unroll
        for (int g = 0; g < 3; ++g) {
            const float4* row = (const float4*)(ewhh + (size_t)(g * 64 + j) * 64);
            #pragma unroll
            for (int k4 = 0; k4 < 16; ++k4) *(float4*)&Wh[g][4 * k4] = row[k4];
        }
        float Wi[3][9];
        #pragma unroll
        for (int g = 0; g < 3; ++g) {
            const float* row = ewih + (g * 64 + j) * 9;
            #pragma unroll
            for (int k = 0; k < 9; ++k) Wi[g][k] = row[k];
        }
        const float bi0 = ebih[j], bi1 = ebih[64 + j], bi2 = ebih[128 + j];
        const float bh0 = ebhh[j], bh1 = ebhh[64 + j], bh2 = ebhh[128 + j];

        __syncthreads();   // xs visible

        #pragma unroll 1
        for (int t = 0; t < L_; ++t) {
            float gr = bi0 + bh0, gz = bi1 + bh1, gni = bi2, gnh = bh2;
            #pragma unroll
            for (int k = 0; k < 9; ++k) {
                const float xk = xs[t * 9 + k];   // same-addr LDS broadcast
                gr  = fmaf(Wi[0][k], xk, gr);
                gz  = fmaf(Wi[1][k], xk, gz);
                gni = fmaf(Wi[2][k], xk, gni);
            }
            #pragma unroll
            for (int k = 0; k < 64; ++k) {
                const float hk = bcast(h, k);
                gr  = fmaf(Wh[0][k], hk, gr);
                gz  = fmaf(Wh[1][k], hk, gz);
                gnh = fmaf(Wh[2][k], hk, gnh);
            }
            const float r = sigmoid_f(gr);
            const float z = sigmoid_f(gz);
            const float n = tanh_f(gni + r * gnh);
            h = (1.f - z) * n + z * h;
        }
    }

    // =================== decoder: 20 steps + lin + cumsum ==================
    {
        float Wh[3][64];
        #pragma unroll
        for (int g = 0; g < 3; ++g) {
            const float4* row = (const float4*)(dwhh + (size_t)(g * 64 + j) * 64);
            #pragma unroll
            for (int k4 = 0; k4 < 16; ++k4) *(float4*)&Wh[g][4 * k4] = row[k4];
        }
        float Wi[3][4];
        #pragma unroll
        for (int g = 0; g < 3; ++g) {
            const float* row = dwih + (g * 64 + j) * 4;
            #pragma unroll
            for (int k = 0; k < 4; ++k) Wi[g][k] = row[k];
        }
        const float bi0 = dbih[j], bi1 = dbih[64 + j], bi2 = dbih[128 + j];
        const float bh0 = dbhh[j], bh1 = dbhh[64 + j], bh2 = dbhh[128 + j];
        const float lw0 = linw[j], lw1 = linw[64 + j], lw2 = linw[128 + j], lw3 = linw[192 + j];
        const float lb0 = linb[0], lb1 = linb[1], lb2 = linb[2], lb3 = linb[3];

        const float* bb = bbox + (size_t)b * 124;
        float px0 = bb[120] - bb[116];
        float px1 = bb[121] - bb[117];
        float px2 = bb[122] - bb[118];
        float px3 = bb[123] - bb[119];
        const float of0 = bb[120], of1 = bb[121], of2 = bb[122], of3 = bb[123];
        float cs0 = 0.f, cs1 = 0.f, cs2 = 0.f, cs3 = 0.f;
        float4* outp = (float4*)(out + (size_t)b * 80);

        #pragma unroll 1
        for (int t = 0; t < 20; ++t) {
            float gr = bi0 + bh0, gz = bi1 + bh1, gni = bi2, gnh = bh2;
            gr  = fmaf(Wi[0][0], px0, fmaf(Wi[0][1], px1, fmaf(Wi[0][2], px2, fmaf(Wi[0][3], px3, gr))));
            gz  = fmaf(Wi[1][0], px0, fmaf(Wi[1][1], px1, fmaf(Wi[1][2], px2, fmaf(Wi[1][3], px3, gz))));
            gni = fmaf(Wi[2][0], px0, fmaf(Wi[2][1], px1, fmaf(Wi[2][2], px2, fmaf(Wi[2][3], px3, gni))));
            #pragma unroll
            for (int k = 0; k < 64; ++k) {
                const float hk = bcast(h, k);
                gr  = fmaf(Wh[0][k], hk, gr);
                gz  = fmaf(Wh[1][k], hk, gz);
                gnh = fmaf(Wh[2][k], hk, gnh);
            }
            const float r = sigmoid_f(gr);
            const float z = sigmoid_f(gz);
            const float n = tanh_f(gni + r * gnh);
            h = (1.f - z) * n + z * h;

            // x_new = lin(h) + prev_x ; 64-lane butterfly
            float v0 = lw0 * h, v1 = lw1 * h, v2 = lw2 * h, v3 = lw3 * h;
            #pragma unroll
            for (int s = 32; s > 0; s >>= 1) {
                v0 += __shfl_xor(v0, s);
                v1 += __shfl_xor(v1, s);
                v2 += __shfl_xor(v2, s);
                v3 += __shfl_xor(v3, s);
            }
            px0 = v0 + lb0 + px0;
            px1 = v1 + lb1 + px1;
            px2 = v2 + lb2 + px2;
            px3 = v3 + lb3 + px3;
            cs0 += px0; cs1 += px1; cs2 += px2; cs3 += px3;
            if (j == 0) outp[t] = make_float4(cs0 + of0, cs1 + of1, cs2 + of2, cs3 + of3);
        }
    }
}

// ---------------------------------------------------------------------------
extern "C" void kernel_launch(void* const* d_in, const int* in_sizes, int n_in,
                              void* d_out, int out_size, void* d_ws, size_t ws_size,
                              hipStream_t stream) {
    (void)in_sizes; (void)n_in; (void)out_size; (void)ws_size;
    const float* bbox = (const float*)d_in[0];
    const float* head = (const float*)d_in[1];
    const float* c1w  = (const float*)d_in[2];
    const float* c1b  = (const float*)d_in[3];
    const float* c2w  = (const float*)d_in[4];
    const float* c2b  = (const float*)d_in[5];
    const float* fcw  = (const float*)d_in[6];
    const float* fcb  = (const float*)d_in[7];
    const float* ewih = (const float*)d_in[8];
    const float* ewhh = (const float*)d_in[9];
    const float* ebih = (const float*)d_in[10];
    const float* ebhh = (const float*)d_in[11];
    const float* dwih = (const float*)d_in[12];
    const float* dwhh = (const float*)d_in[13];
    const float* dbih = (const float*)d_in[14];
    const float* dbhh = (const float*)d_in[15];
    const float* linw = (const float*)d_in[16];
    const float* linb = (const float*)d_in[17];
    float* out = (float*)d_out;

    float* enc_in = (float*)d_ws;   // 1024*30*9 floats

    conv_embed_kernel<<<B_ * L_, 64, 0, stream>>>(bbox, head, c1w, c1b, c2w, c2b,
                                                  fcw, fcb, enc_in);
    gru_encdec_kernel<<<B_, 64, 0, stream>>>(bbox, enc_in,
                                             ewih, ewhh, ebih, ebhh,
                                             dwih, dwhh, dbih, dbhh,
                                             linw, linb, out);
}

// Round 8
// 298.307 us; speedup vs baseline: 1.7621x; 1.0740x over previous
//
#include <hip/hip_runtime.h>
#include <hip/hip_bf16.h>

// ---------------------------------------------------------------------------
// Split pipeline:
//   K1 conv_embed : R1 algorithm + unroll-by-2 rolling windows (no reg-copy
//                   movs; mod-6 slot rotation). Issue-bound -> fewer instrs.
//   K2 gru_encdec : one wave per batch element, launch_bounds(64,1).
//                   Hidden matvec via v_dot2_f32_f16 (fdot2) on f16-packed
//                   weights (96 VGPRs/phase); h broadcast through same-address
//                   LDS half2 reads (free broadcast, wave-synchronous).
// ---------------------------------------------------------------------------

#define B_    1024
#define L_    30
#define H_    64

typedef _Float16 half_t;
typedef __attribute__((ext_vector_type(2))) _Float16 half2_t;

__device__ __forceinline__ float sigmoid_f(float v) {
    return 1.f / (1.f + __expf(-v));
}
__device__ __forceinline__ float tanh_f(float v) {
    v = fminf(fmaxf(v, -15.f), 15.f);
    float e = __expf(2.f * v);
    return (e - 1.f) / (e + 1.f);
}
__device__ __forceinline__ void load4_lds(float* r, const float* p) {
    float2 a = *(const float2*)p;
    float2 b = *(const float2*)(p + 2);
    r[0] = a.x; r[1] = a.y; r[2] = b.x; r[3] = b.y;
}

// ---------------------------------------------------------------------------
// Kernel A: per-image conv encoder + fc. One 64-thread block per image.
// ---------------------------------------------------------------------------
__global__ __launch_bounds__(64) void conv_embed_kernel(
    const float* __restrict__ bbox,
    const float* __restrict__ head,
    const float* __restrict__ c1w, const float* __restrict__ c1b,
    const float* __restrict__ c2w, const float* __restrict__ c2b,
    const float* __restrict__ fcw, const float* __restrict__ fcb,
    float* __restrict__ enc_in)
{
    const int img = blockIdx.x;          // 0..30719
    const int b = img / L_;
    const int l = img % L_;
    const int tid = threadIdx.x;

    __shared__ float s_img[32 * 32];
    __shared__ float s_p1[4 * 15 * 16];  // [c][py][px], width padded to 16
    __shared__ float s_p2[360];
    __shared__ float s_red[60];

    {
        const float4* src = (const float4*)(head + ((size_t)b * 31 + (size_t)l) * 1024);
        float4* dst = (float4*)s_img;
        #pragma unroll
        for (int i = 0; i < 4; ++i) dst[tid + 64 * i] = src[tid + 64 * i];
    }
    __syncthreads();

    // stage 1: conv1 + relu + pool; thread=(c,px); unroll-by-2, mod-6 slots
    if (tid < 60) {
        const int c = tid / 15, px = tid % 15;
        const int x0 = 2 * px;
        float wg[9];
        #pragma unroll
        for (int k = 0; k < 9; ++k) wg[k] = c1w[c * 9 + k];
        const float bias = c1b[c];

        auto c1out = [&](const float* ra, const float* rb, const float* rc, const float* rd) -> float {
            float a00 = bias, a01 = bias, a10 = bias, a11 = bias;
            #pragma unroll
            for (int kx = 0; kx < 3; ++kx) {
                const float w0 = wg[kx], w1 = wg[3 + kx], w2 = wg[6 + kx];
                a00 = fmaf(w0, ra[kx],     fmaf(w1, rb[kx],     fmaf(w2, rc[kx],     a00)));
                a01 = fmaf(w0, ra[kx + 1], fmaf(w1, rb[kx + 1], fmaf(w2, rc[kx + 1], a01)));
                a10 = fmaf(w0, rb[kx],     fmaf(w1, rc[kx],     fmaf(w2, rd[kx],     a10)));
                a11 = fmaf(w0, rb[kx + 1], fmaf(w1, rc[kx + 1], fmaf(w2, rd[kx + 1], a11)));
            }
            a00 = fmaxf(a00, 0.f); a01 = fmaxf(a01, 0.f);
            a10 = fmaxf(a10, 0.f); a11 = fmaxf(a11, 0.f);
            return fmaxf(fmaxf(a00, a01), fmaxf(a10, a11));
        };

        float r[6][4];
        load4_lds(r[0], s_img + 0 * 32 + x0);
        load4_lds(r[1], s_img + 1 * 32 + x0);
        #pragma unroll
        for (int i = 0; i < 7; ++i) {
            const int s0 = (4 * i) % 6, s1 = (4 * i + 1) % 6, s2 = (4 * i + 2) % 6;
            const int s3 = (4 * i + 3) % 6, s4 = (4 * i + 4) % 6, s5 = (4 * i + 5) % 6;
            load4_lds(r[s2], s_img + (4 * i + 2) * 32 + x0);
            load4_lds(r[s3], s_img + (4 * i + 3) * 32 + x0);
            s_p1[c * 240 + (2 * i) * 16 + px] = c1out(r[s0], r[s1], r[s2], r[s3]);
            load4_lds(r[s4], s_img + (4 * i + 4) * 32 + x0);
            load4_lds(r[s5], s_img + (4 * i + 5) * 32 + x0);
            s_p1[c * 240 + (2 * i + 1) * 16 + px] = c1out(r[s2], r[s3], r[s4], r[s5]);
        }
        // tail py=14: rows 28(s4),29(s5),30,31
        load4_lds(r[0], s_img + 30 * 32 + x0);
        load4_lds(r[1], s_img + 31 * 32 + x0);
        s_p1[c * 240 + 14 * 16 + px] = c1out(r[4], r[5], r[0], r[1]);
    }
    __syncthreads();

    // stage 2: conv2 + relu + pool; thread=(c,px); unroll-by-2, mod-6 slots
    if (tid < 60) {
        const int c = tid / 6, px = tid % 6;
        const int x0 = 2 * px;
        float wg2[4][9];
        #pragma unroll
        for (int ic = 0; ic < 4; ++ic)
            #pragma unroll
            for (int k = 0; k < 9; ++k) wg2[ic][k] = c2w[(c * 4 + ic) * 9 + k];
        const float bias2 = c2b[c];

        float P[6][4][4];   // [row slot][ic][col]
        auto c2out = [&](float (*pa)[4], float (*pb)[4], float (*pc)[4], float (*pd)[4]) -> float {
            float a00 = bias2, a01 = bias2, a10 = bias2, a11 = bias2;
            #pragma unroll
            for (int ic = 0; ic < 4; ++ic) {
                #pragma unroll
                for (int kx = 0; kx < 3; ++kx) {
                    const float w0 = wg2[ic][kx], w1 = wg2[ic][3 + kx], w2 = wg2[ic][6 + kx];
                    a00 = fmaf(w0, pa[ic][kx],     fmaf(w1, pb[ic][kx],     fmaf(w2, pc[ic][kx],     a00)));
                    a01 = fmaf(w0, pa[ic][kx + 1], fmaf(w1, pb[ic][kx + 1], fmaf(w2, pc[ic][kx + 1], a01)));
                    a10 = fmaf(w0, pb[ic][kx],     fmaf(w1, pc[ic][kx],     fmaf(w2, pd[ic][kx],     a10)));
                    a11 = fmaf(w0, pb[ic][kx + 1], fmaf(w1, pc[ic][kx + 1], fmaf(w2, pd[ic][kx + 1], a11)));
                }
            }
            a00 = fmaxf(a00, 0.f); a01 = fmaxf(a01, 0.f);
            a10 = fmaxf(a10, 0.f); a11 = fmaxf(a11, 0.f);
            return fmaxf(fmaxf(a00, a01), fmaxf(a10, a11));
        };

        #pragma unroll
        for (int ic = 0; ic < 4; ++ic) {
            load4_lds(P[0][ic], s_p1 + ic * 240 + 0 * 16 + x0);
            load4_lds(P[1][ic], s_p1 + ic * 240 + 1 * 16 + x0);
        }
        #pragma unroll
        for (int i = 0; i < 3; ++i) {
            const int s0 = (4 * i) % 6, s1 = (4 * i + 1) % 6, s2 = (4 * i + 2) % 6;
            const int s3 = (4 * i + 3) % 6, s4 = (4 * i + 4) % 6, s5 = (4 * i + 5) % 6;
            #pragma unroll
            for (int ic = 0; ic < 4; ++ic) {
                load4_lds(P[s2][ic], s_p1 + ic * 240 + (4 * i + 2) * 16 + x0);
                load4_lds(P[s3][ic], s_p1 + ic * 240 + (4 * i + 3) * 16 + x0);
            }
            s_p2[c * 36 + (2 * i) * 6 + px] = c2out(P[s0], P[s1], P[s2], P[s3]);
            #pragma unroll
            for (int ic = 0; ic < 4; ++ic) {
                load4_lds(P[s4][ic], s_p1 + ic * 240 + (4 * i + 4) * 16 + x0);
                load4_lds(P[s5][ic], s_p1 + ic * 240 + (4 * i + 5) * 16 + x0);
            }
            s_p2[c * 36 + (2 * i + 1) * 6 + px] = c2out(P[s2], P[s3], P[s4], P[s5]);
        }
    }
    __syncthreads();

    // stage 3: fc 360->5
    if (tid < 60) {
        const int o = tid / 12, i0 = tid % 12;
        const float* wrow = fcw + o * 360;
        float acc = 0.f;
        #pragma unroll
        for (int k = 0; k < 30; ++k) {
            const int i = i0 + 12 * k;
            acc = fmaf(wrow[i], s_p2[i], acc);
        }
        s_red[tid] = acc;
    }
    __syncthreads();

    float* dst = enc_in + ((size_t)b * L_ + l) * 9;
    if (tid < 5) {
        float acc = fcb[tid];
        #pragma unroll
        for (int k = 0; k < 12; ++k) acc += s_red[tid * 12 + k];
        dst[4 + tid] = acc;
    } else if (tid >= 8 && tid < 12) {
        const int d = tid - 8;
        const float* bb = bbox + (size_t)b * 124 + (size_t)l * 4;
        dst[d] = bb[4 + d] - bb[d];
    }
}

// ---------------------------------------------------------------------------
// Kernel B: encoder + decoder, ONE WAVE per batch element, fdot2 matvec.
// ---------------------------------------------------------------------------
__global__ __launch_bounds__(64, 1) void gru_encdec_kernel(
    const float* __restrict__ bbox,     // [1024][31][4]
    const float* __restrict__ enc_in,   // [1024][30][9]
    const float* __restrict__ ewih, const float* __restrict__ ewhh,
    const float* __restrict__ ebih, const float* __restrict__ ebhh,
    const float* __restrict__ dwih, const float* __restrict__ dwhh,
    const float* __restrict__ dbih, const float* __restrict__ dbhh,
    const float* __restrict__ linw, const float* __restrict__ linb,
    float* __restrict__ out)            // [1024][20][4]
{
    const int b = blockIdx.x;
    const int j = threadIdx.x;          // 0..63

    __shared__ float  xs[272];          // enc_in[b]
    __shared__ half_t hs[64];           // h broadcast buffer (f16)

    for (int i = j; i < 270; i += 64) xs[i] = enc_in[(size_t)b * 270 + i];

    float h = 0.f;

    // =================== encoder: 30 steps =================================
    {
        half2_t Wh2[3][32];
        #pragma unroll
        for (int g = 0; g < 3; ++g) {
            const float4* row = (const float4*)(ewhh + (size_t)(g * 64 + j) * 64);
            #pragma unroll
            for (int k4 = 0; k4 < 16; ++k4) {
                const float4 v = row[k4];
                Wh2[g][2 * k4]     = half2_t{(half_t)v.x, (half_t)v.y};
                Wh2[g][2 * k4 + 1] = half2_t{(half_t)v.z, (half_t)v.w};
            }
        }
        float Wi[3][9];
        #pragma unroll
        for (int g = 0; g < 3; ++g) {
            const float* row = ewih + (g * 64 + j) * 9;
            #pragma unroll
            for (int k = 0; k < 9; ++k) Wi[g][k] = row[k];
        }
        const float bi0 = ebih[j], bi1 = ebih[64 + j], bi2 = ebih[128 + j];
        const float bh0 = ebhh[j], bh1 = ebhh[64 + j], bh2 = ebhh[128 + j];

        __syncthreads();   // xs visible (single wave; cheap)

        #pragma unroll 1
        for (int t = 0; t < L_; ++t) {
            hs[j] = (half_t)h;                       // wave-synchronous publish
            __builtin_amdgcn_wave_barrier();         // compiler ordering fence

            float gr = bi0 + bh0, gz = bi1 + bh1, gni = bi2, gnh = bh2;
            #pragma unroll
            for (int k = 0; k < 9; ++k) {
                const float xk = xs[t * 9 + k];      // same-addr LDS broadcast
                gr  = fmaf(Wi[0][k], xk, gr);
                gz  = fmaf(Wi[1][k], xk, gz);
                gni = fmaf(Wi[2][k], xk, gni);
            }
            const half2_t* hp = (const half2_t*)hs;
            #pragma unroll
            for (int k2 = 0; k2 < 32; ++k2) {
                const half2_t h2 = hp[k2];           // same-addr broadcast read
                gr  = __builtin_amdgcn_fdot2(Wh2[0][k2], h2, gr,  false);
                gz  = __builtin_amdgcn_fdot2(Wh2[1][k2], h2, gz,  false);
                gnh = __builtin_amdgcn_fdot2(Wh2[2][k2], h2, gnh, false);
            }
            const float r = sigmoid_f(gr);
            const float z = sigmoid_f(gz);
            const float n = tanh_f(gni + r * gnh);
            h = (1.f - z) * n + z * h;
            __builtin_amdgcn_wave_barrier();         // keep next write after reads
        }
    }

    // =================== decoder: 20 steps + lin + cumsum ==================
    {
        half2_t Wh2[3][32];
        #pragma unroll
        for (int g = 0; g < 3; ++g) {
            const float4* row = (const float4*)(dwhh + (size_t)(g * 64 + j) * 64);
            #pragma unroll
            for (int k4 = 0; k4 < 16; ++k4) {
                const float4 v = row[k4];
                Wh2[g][2 * k4]     = half2_t{(half_t)v.x, (half_t)v.y};
                Wh2[g][2 * k4 + 1] = half2_t{(half_t)v.z, (half_t)v.w};
            }
        }
        float Wi[3][4];
        #pragma unroll
        for (int g = 0; g < 3; ++g) {
            const float* row = dwih + (g * 64 + j) * 4;
            #pragma unroll
            for (int k = 0; k < 4; ++k) Wi[g][k] = row[k];
        }
        const float bi0 = dbih[j], bi1 = dbih[64 + j], bi2 = dbih[128 + j];
        const float bh0 = dbhh[j], bh1 = dbhh[64 + j], bh2 = dbhh[128 + j];
        const float lw0 = linw[j], lw1 = linw[64 + j], lw2 = linw[128 + j], lw3 = linw[192 + j];
        const float lb0 = linb[0], lb1 = linb[1], lb2 = linb[2], lb3 = linb[3];

        const float* bb = bbox + (size_t)b * 124;
        float px0 = bb[120] - bb[116];
        float px1 = bb[121] - bb[117];
        float px2 = bb[122] - bb[118];
        float px3 = bb[123] - bb[119];
        const float of0 = bb[120], of1 = bb[121], of2 = bb[122], of3 = bb[123];
        float cs0 = 0.f, cs1 = 0.f, cs2 = 0.f, cs3 = 0.f;
        float4* outp = (float4*)(out + (size_t)b * 80);

        #pragma unroll 1
        for (int t = 0; t < 20; ++t) {
            hs[j] = (half_t)h;
            __builtin_amdgcn_wave_barrier();

            float gr = bi0 + bh0, gz = bi1 + bh1, gni = bi2, gnh = bh2;
            gr  = fmaf(Wi[0][0], px0, fmaf(Wi[0][1], px1, fmaf(Wi[0][2], px2, fmaf(Wi[0][3], px3, gr))));
            gz  = fmaf(Wi[1][0], px0, fmaf(Wi[1][1], px1, fmaf(Wi[1][2], px2, fmaf(Wi[1][3], px3, gz))));
            gni = fmaf(Wi[2][0], px0, fmaf(Wi[2][1], px1, fmaf(Wi[2][2], px2, fmaf(Wi[2][3], px3, gni))));

            const half2_t* hp = (const half2_t*)hs;
            #pragma unroll
            for (int k2 = 0; k2 < 32; ++k2) {
                const half2_t h2 = hp[k2];
                gr  = __builtin_amdgcn_fdot2(Wh2[0][k2], h2, gr,  false);
                gz  = __builtin_amdgcn_fdot2(Wh2[1][k2], h2, gz,  false);
                gnh = __builtin_amdgcn_fdot2(Wh2[2][k2], h2, gnh, false);
            }
            const float r = sigmoid_f(gr);
            const float z = sigmoid_f(gz);
            const float n = tanh_f(gni + r * gnh);
            h = (1.f - z) * n + z * h;
            __builtin_amdgcn_wave_barrier();

            // x_new = lin(h) + prev_x ; 64-lane butterfly
            float v0 = lw0 * h, v1 = lw1 * h, v2 = lw2 * h, v3 = lw3 * h;
            #pragma unroll
            for (int s = 32; s > 0; s >>= 1) {
                v0 += __shfl_xor(v0, s);
                v1 += __shfl_xor(v1, s);
                v2 += __shfl_xor(v2, s);
                v3 += __shfl_xor(v3, s);
            }
            px0 = v0 + lb0 + px0;
            px1 = v1 + lb1 + px1;
            px2 = v2 + lb2 + px2;
            px3 = v3 + lb3 + px3;
            cs0 += px0; cs1 += px1; cs2 += px2; cs3 += px3;
            if (j == 0) outp[t] = make_float4(cs0 + of0, cs1 + of1, cs2 + of2, cs3 + of3);
        }
    }
}

// ---------------------------------------------------------------------------
extern "C" void kernel_launch(void* const* d_in, const int* in_sizes, int n_in,
                              void* d_out, int out_size, void* d_ws, size_t ws_size,
                              hipStream_t stream) {
    (void)in_sizes; (void)n_in; (void)out_size; (void)ws_size;
    const float* bbox = (const float*)d_in[0];
    const float* head = (const float*)d_in[1];
    const float* c1w  = (const float*)d_in[2];
    const float* c1b  = (const float*)d_in[3];
    const float* c2w  = (const float*)d_in[4];
    const float* c2b  = (const float*)d_in[5];
    const float* fcw  = (const float*)d_in[6];
    const float* fcb  = (const float*)d_in[7];
    const float* ewih = (const float*)d_in[8];
    const float* ewhh = (const float*)d_in[9];
    const float* ebih = (const float*)d_in[10];
    const float* ebhh = (const float*)d_in[11];
    const float* dwih = (const float*)d_in[12];
    const float* dwhh = (const float*)d_in[13];
    const float* dbih = (const float*)d_in[14];
    const float* dbhh = (const float*)d_in[15];
    const float* linw = (const float*)d_in[16];
    const float* linb = (const float*)d_in[17];
    float* out = (float*)d_out;

    float* enc_in = (float*)d_ws;   // 1024*30*9 floats

    conv_embed_kernel<<<B_ * L_, 64, 0, stream>>>(bbox, head, c1w, c1b, c2w, c2b,
                                                  fcw, fcb, enc_in);
    gru_encdec_kernel<<<B_, 64, 0, stream>>>(bbox, enc_in,
                                             ewih, ewhh, ebih, ebhh,
                                             dwih, dwhh, dbih, dbhh,
                                             linw, linb, out);
}

// Round 9
// 295.316 us; speedup vs baseline: 1.7799x; 1.0101x over previous
//
#include <hip/hip_runtime.h>
#include <hip/hip_bf16.h>

// ---------------------------------------------------------------------------
// Split pipeline:
//   K1 conv_embed : R8 kernel (~88.6us, VALU-issue-bound).
//   K2 gru_encdec : one wave per batch element, launch_bounds(64,1).
//     R9 fix: h broadcast read as 8x ds_read_b128 into regs (ONE lgkmcnt wait
//     instead of 32 interleaved load-waits ~ 120cyc each at 1 wave/SIMD),
//     publish at loop bottom, rcp-based activations. fdot2 matvec from regs.
// ---------------------------------------------------------------------------

#define B_    1024
#define L_    30
#define H_    64

typedef _Float16 half_t;
typedef __attribute__((ext_vector_type(2))) _Float16 half2_t;
typedef __attribute__((ext_vector_type(8))) _Float16 half8_t;

__device__ __forceinline__ float sigmoid_f(float v) {
    return __builtin_amdgcn_rcpf(1.f + __expf(-v));
}
__device__ __forceinline__ float tanh_f(float v) {
    v = fminf(fmaxf(v, -15.f), 15.f);
    const float e = __expf(2.f * v);
    return (e - 1.f) * __builtin_amdgcn_rcpf(e + 1.f);
}
__device__ __forceinline__ void load4_lds(float* r, const float* p) {
    float2 a = *(const float2*)p;
    float2 b = *(const float2*)(p + 2);
    r[0] = a.x; r[1] = a.y; r[2] = b.x; r[3] = b.y;
}

// ---------------------------------------------------------------------------
// Kernel A: per-image conv encoder + fc. One 64-thread block per image.
// ---------------------------------------------------------------------------
__global__ __launch_bounds__(64) void conv_embed_kernel(
    const float* __restrict__ bbox,
    const float* __restrict__ head,
    const float* __restrict__ c1w, const float* __restrict__ c1b,
    const float* __restrict__ c2w, const float* __restrict__ c2b,
    const float* __restrict__ fcw, const float* __restrict__ fcb,
    float* __restrict__ enc_in)
{
    const int img = blockIdx.x;          // 0..30719
    const int b = img / L_;
    const int l = img % L_;
    const int tid = threadIdx.x;

    __shared__ float s_img[32 * 32];
    __shared__ float s_p1[4 * 15 * 16];  // [c][py][px], width padded to 16
    __shared__ float s_p2[360];
    __shared__ float s_red[60];

    {
        const float4* src = (const float4*)(head + ((size_t)b * 31 + (size_t)l) * 1024);
        float4* dst = (float4*)s_img;
        #pragma unroll
        for (int i = 0; i < 4; ++i) dst[tid + 64 * i] = src[tid + 64 * i];
    }
    __syncthreads();

    // stage 1: conv1 + relu + pool; thread=(c,px); unroll-by-2, mod-6 slots
    if (tid < 60) {
        const int c = tid / 15, px = tid % 15;
        const int x0 = 2 * px;
        float wg[9];
        #pragma unroll
        for (int k = 0; k < 9; ++k) wg[k] = c1w[c * 9 + k];
        const float bias = c1b[c];

        auto c1out = [&](const float* ra, const float* rb, const float* rc, const float* rd) -> float {
            float a00 = bias, a01 = bias, a10 = bias, a11 = bias;
            #pragma unroll
            for (int kx = 0; kx < 3; ++kx) {
                const float w0 = wg[kx], w1 = wg[3 + kx], w2 = wg[6 + kx];
                a00 = fmaf(w0, ra[kx],     fmaf(w1, rb[kx],     fmaf(w2, rc[kx],     a00)));
                a01 = fmaf(w0, ra[kx + 1], fmaf(w1, rb[kx + 1], fmaf(w2, rc[kx + 1], a01)));
                a10 = fmaf(w0, rb[kx],     fmaf(w1, rc[kx],     fmaf(w2, rd[kx],     a10)));
                a11 = fmaf(w0, rb[kx + 1], fmaf(w1, rc[kx + 1], fmaf(w2, rd[kx + 1], a11)));
            }
            a00 = fmaxf(a00, 0.f); a01 = fmaxf(a01, 0.f);
            a10 = fmaxf(a10, 0.f); a11 = fmaxf(a11, 0.f);
            return fmaxf(fmaxf(a00, a01), fmaxf(a10, a11));
        };

        float r[6][4];
        load4_lds(r[0], s_img + 0 * 32 + x0);
        load4_lds(r[1], s_img + 1 * 32 + x0);
        #pragma unroll
        for (int i = 0; i < 7; ++i) {
            const int s0 = (4 * i) % 6, s1 = (4 * i + 1) % 6, s2 = (4 * i + 2) % 6;
            const int s3 = (4 * i + 3) % 6, s4 = (4 * i + 4) % 6, s5 = (4 * i + 5) % 6;
            load4_lds(r[s2], s_img + (4 * i + 2) * 32 + x0);
            load4_lds(r[s3], s_img + (4 * i + 3) * 32 + x0);
            s_p1[c * 240 + (2 * i) * 16 + px] = c1out(r[s0], r[s1], r[s2], r[s3]);
            load4_lds(r[s4], s_img + (4 * i + 4) * 32 + x0);
            load4_lds(r[s5], s_img + (4 * i + 5) * 32 + x0);
            s_p1[c * 240 + (2 * i + 1) * 16 + px] = c1out(r[s2], r[s3], r[s4], r[s5]);
        }
        // tail py=14: rows 28(s4),29(s5),30,31
        load4_lds(r[0], s_img + 30 * 32 + x0);
        load4_lds(r[1], s_img + 31 * 32 + x0);
        s_p1[c * 240 + 14 * 16 + px] = c1out(r[4], r[5], r[0], r[1]);
    }
    __syncthreads();

    // stage 2: conv2 + relu + pool; thread=(c,px); unroll-by-2, mod-6 slots
    if (tid < 60) {
        const int c = tid / 6, px = tid % 6;
        const int x0 = 2 * px;
        float wg2[4][9];
        #pragma unroll
        for (int ic = 0; ic < 4; ++ic)
            #pragma unroll
            for (int k = 0; k < 9; ++k) wg2[ic][k] = c2w[(c * 4 + ic) * 9 + k];
        const float bias2 = c2b[c];

        float P[6][4][4];   // [row slot][ic][col]
        auto c2out = [&](float (*pa)[4], float (*pb)[4], float (*pc)[4], float (*pd)[4]) -> float {
            float a00 = bias2, a01 = bias2, a10 = bias2, a11 = bias2;
            #pragma unroll
            for (int ic = 0; ic < 4; ++ic) {
                #pragma unroll
                for (int kx = 0; kx < 3; ++kx) {
                    const float w0 = wg2[ic][kx], w1 = wg2[ic][3 + kx], w2 = wg2[ic][6 + kx];
                    a00 = fmaf(w0, pa[ic][kx],     fmaf(w1, pb[ic][kx],     fmaf(w2, pc[ic][kx],     a00)));
                    a01 = fmaf(w0, pa[ic][kx + 1], fmaf(w1, pb[ic][kx + 1], fmaf(w2, pc[ic][kx + 1], a01)));
                    a10 = fmaf(w0, pb[ic][kx],     fmaf(w1, pc[ic][kx],     fmaf(w2, pd[ic][kx],     a10)));
                    a11 = fmaf(w0, pb[ic][kx + 1], fmaf(w1, pc[ic][kx + 1], fmaf(w2, pd[ic][kx + 1], a11)));
                }
            }
            a00 = fmaxf(a00, 0.f); a01 = fmaxf(a01, 0.f);
            a10 = fmaxf(a10, 0.f); a11 = fmaxf(a11, 0.f);
            return fmaxf(fmaxf(a00, a01), fmaxf(a10, a11));
        };

        #pragma unroll
        for (int ic = 0; ic < 4; ++ic) {
            load4_lds(P[0][ic], s_p1 + ic * 240 + 0 * 16 + x0);
            load4_lds(P[1][ic], s_p1 + ic * 240 + 1 * 16 + x0);
        }
        #pragma unroll
        for (int i = 0; i < 3; ++i) {
            const int s0 = (4 * i) % 6, s1 = (4 * i + 1) % 6, s2 = (4 * i + 2) % 6;
            const int s3 = (4 * i + 3) % 6, s4 = (4 * i + 4) % 6, s5 = (4 * i + 5) % 6;
            #pragma unroll
            for (int ic = 0; ic < 4; ++ic) {
                load4_lds(P[s2][ic], s_p1 + ic * 240 + (4 * i + 2) * 16 + x0);
                load4_lds(P[s3][ic], s_p1 + ic * 240 + (4 * i + 3) * 16 + x0);
            }
            s_p2[c * 36 + (2 * i) * 6 + px] = c2out(P[s0], P[s1], P[s2], P[s3]);
            #pragma unroll
            for (int ic = 0; ic < 4; ++ic) {
                load4_lds(P[s4][ic], s_p1 + ic * 240 + (4 * i + 4) * 16 + x0);
                load4_lds(P[s5][ic], s_p1 + ic * 240 + (4 * i + 5) * 16 + x0);
            }
            s_p2[c * 36 + (2 * i + 1) * 6 + px] = c2out(P[s2], P[s3], P[s4], P[s5]);
        }
    }
    __syncthreads();

    // stage 3: fc 360->5
    if (tid < 60) {
        const int o = tid / 12, i0 = tid % 12;
        const float* wrow = fcw + o * 360;
        float acc = 0.f;
        #pragma unroll
        for (int k = 0; k < 30; ++k) {
            const int i = i0 + 12 * k;
            acc = fmaf(wrow[i], s_p2[i], acc);
        }
        s_red[tid] = acc;
    }
    __syncthreads();

    float* dst = enc_in + ((size_t)b * L_ + l) * 9;
    if (tid < 5) {
        float acc = fcb[tid];
        #pragma unroll
        for (int k = 0; k < 12; ++k) acc += s_red[tid * 12 + k];
        dst[4 + tid] = acc;
    } else if (tid >= 8 && tid < 12) {
        const int d = tid - 8;
        const float* bb = bbox + (size_t)b * 124 + (size_t)l * 4;
        dst[d] = bb[4 + d] - bb[d];
    }
}

// ---------------------------------------------------------------------------
// Kernel B: encoder + decoder, ONE WAVE per batch element, fdot2 matvec.
// h broadcast: publish (ds_write_b16) at loop bottom; read back at loop top
// as 8x ds_read_b128 into registers (single lgkmcnt drain).
// ---------------------------------------------------------------------------
__global__ __launch_bounds__(64, 1) void gru_encdec_kernel(
    const float* __restrict__ bbox,     // [1024][31][4]
    const float* __restrict__ enc_in,   // [1024][30][9]
    const float* __restrict__ ewih, const float* __restrict__ ewhh,
    const float* __restrict__ ebih, const float* __restrict__ ebhh,
    const float* __restrict__ dwih, const float* __restrict__ dwhh,
    const float* __restrict__ dbih, const float* __restrict__ dbhh,
    const float* __restrict__ linw, const float* __restrict__ linb,
    float* __restrict__ out)            // [1024][20][4]
{
    const int b = blockIdx.x;
    const int j = threadIdx.x;          // 0..63

    __shared__ float xs[272];                 // enc_in[b]
    __shared__ alignas(16) half_t hs[64];     // h broadcast buffer (f16)

    for (int i = j; i < 270; i += 64) xs[i] = enc_in[(size_t)b * 270 + i];
    hs[j] = (half_t)0.f;                      // initial h

    float h = 0.f;

    // =================== encoder: 30 steps =================================
    {
        half2_t Wh2[3][32];
        #pragma unroll
        for (int g = 0; g < 3; ++g) {
            const float4* row = (const float4*)(ewhh + (size_t)(g * 64 + j) * 64);
            #pragma unroll
            for (int k4 = 0; k4 < 16; ++k4) {
                const float4 v = row[k4];
                Wh2[g][2 * k4]     = half2_t{(half_t)v.x, (half_t)v.y};
                Wh2[g][2 * k4 + 1] = half2_t{(half_t)v.z, (half_t)v.w};
            }
        }
        float Wi[3][9];
        #pragma unroll
        for (int g = 0; g < 3; ++g) {
            const float* row = ewih + (g * 64 + j) * 9;
            #pragma unroll
            for (int k = 0; k < 9; ++k) Wi[g][k] = row[k];
        }
        const float bi0 = ebih[j], bi1 = ebih[64 + j], bi2 = ebih[128 + j];
        const float bh0 = ebhh[j], bh1 = ebhh[64 + j], bh2 = ebhh[128 + j];

        __syncthreads();   // xs + hs visible (single wave; cheap)

        #pragma unroll 1
        for (int t = 0; t < L_; ++t) {
            // batched h read-back: 8 x b128, one drain
            half2_t hv[32];
            {
                const half8_t* hp = (const half8_t*)hs;
                #pragma unroll
                for (int q = 0; q < 8; ++q) *(half8_t*)&hv[4 * q] = hp[q];
            }
            // x side (independent of the LDS reads -> overlaps the wait)
            float gr = bi0 + bh0, gz = bi1 + bh1, gni = bi2, gnh = bh2;
            #pragma unroll
            for (int k = 0; k < 9; ++k) {
                const float xk = xs[t * 9 + k];
                gr  = fmaf(Wi[0][k], xk, gr);
                gz  = fmaf(Wi[1][k], xk, gz);
                gni = fmaf(Wi[2][k], xk, gni);
            }
            #pragma unroll
            for (int k2 = 0; k2 < 32; ++k2) {
                const half2_t h2 = hv[k2];
                gr  = __builtin_amdgcn_fdot2(Wh2[0][k2], h2, gr,  false);
                gz  = __builtin_amdgcn_fdot2(Wh2[1][k2], h2, gz,  false);
                gnh = __builtin_amdgcn_fdot2(Wh2[2][k2], h2, gnh, false);
            }
            const float r = sigmoid_f(gr);
            const float z = sigmoid_f(gz);
            const float n = tanh_f(gni + r * gnh);
            h = fmaf(z, h - n, n);
            hs[j] = (half_t)h;                   // publish for next step
            __builtin_amdgcn_wave_barrier();
        }
    }

    // =================== decoder: 20 steps + lin + cumsum ==================
    {
        half2_t Wh2[3][32];
        #pragma unroll
        for (int g = 0; g < 3; ++g) {
            const float4* row = (const float4*)(dwhh + (size_t)(g * 64 + j) * 64);
            #pragma unroll
            for (int k4 = 0; k4 < 16; ++k4) {
                const float4 v = row[k4];
                Wh2[g][2 * k4]     = half2_t{(half_t)v.x, (half_t)v.y};
                Wh2[g][2 * k4 + 1] = half2_t{(half_t)v.z, (half_t)v.w};
            }
        }
        float Wi[3][4];
        #pragma unroll
        for (int g = 0; g < 3; ++g) {
            const float* row = dwih + (g * 64 + j) * 4;
            #pragma unroll
            for (int k = 0; k < 4; ++k) Wi[g][k] = row[k];
        }
        const float bi0 = dbih[j], bi1 = dbih[64 + j], bi2 = dbih[128 + j];
        const float bh0 = dbhh[j], bh1 = dbhh[64 + j], bh2 = dbhh[128 + j];
        const float lw0 = linw[j], lw1 = linw[64 + j], lw2 = linw[128 + j], lw3 = linw[192 + j];
        const float lb0 = linb[0], lb1 = linb[1], lb2 = linb[2], lb3 = linb[3];

        const float* bb = bbox + (size_t)b * 124;
        float px0 = bb[120] - bb[116];
        float px1 = bb[121] - bb[117];
        float px2 = bb[122] - bb[118];
        float px3 = bb[123] - bb[119];
        const float of0 = bb[120], of1 = bb[121], of2 = bb[122], of3 = bb[123];
        float cs0 = 0.f, cs1 = 0.f, cs2 = 0.f, cs3 = 0.f;
        float4* outp = (float4*)(out + (size_t)b * 80);

        #pragma unroll 1
        for (int t = 0; t < 20; ++t) {
            half2_t hv[32];
            {
                const half8_t* hp = (const half8_t*)hs;
                #pragma unroll
                for (int q = 0; q < 8; ++q) *(half8_t*)&hv[4 * q] = hp[q];
            }
            float gr = bi0 + bh0, gz = bi1 + bh1, gni = bi2, gnh = bh2;
            gr  = fmaf(Wi[0][0], px0, fmaf(Wi[0][1], px1, fmaf(Wi[0][2], px2, fmaf(Wi[0][3], px3, gr))));
            gz  = fmaf(Wi[1][0], px0, fmaf(Wi[1][1], px1, fmaf(Wi[1][2], px2, fmaf(Wi[1][3], px3, gz))));
            gni = fmaf(Wi[2][0], px0, fmaf(Wi[2][1], px1, fmaf(Wi[2][2], px2, fmaf(Wi[2][3], px3, gni))));

            #pragma unroll
            for (int k2 = 0; k2 < 32; ++k2) {
                const half2_t h2 = hv[k2];
                gr  = __builtin_amdgcn_fdot2(Wh2[0][k2], h2, gr,  false);
                gz  = __builtin_amdgcn_fdot2(Wh2[1][k2], h2, gz,  false);
                gnh = __builtin_amdgcn_fdot2(Wh2[2][k2], h2, gnh, false);
            }
            const float r = sigmoid_f(gr);
            const float z = sigmoid_f(gz);
            const float n = tanh_f(gni + r * gnh);
            h = fmaf(z, h - n, n);
            hs[j] = (half_t)h;                   // publish early: write latency
            __builtin_amdgcn_wave_barrier();     // hides under the butterfly

            // x_new = lin(h) + prev_x ; 64-lane butterfly
            float v0 = lw0 * h, v1 = lw1 * h, v2 = lw2 * h, v3 = lw3 * h;
            #pragma unroll
            for (int s = 32; s > 0; s >>= 1) {
                v0 += __shfl_xor(v0, s);
                v1 += __shfl_xor(v1, s);
                v2 += __shfl_xor(v2, s);
                v3 += __shfl_xor(v3, s);
            }
            px0 = v0 + lb0 + px0;
            px1 = v1 + lb1 + px1;
            px2 = v2 + lb2 + px2;
            px3 = v3 + lb3 + px3;
            cs0 += px0; cs1 += px1; cs2 += px2; cs3 += px3;
            if (j == 0) outp[t] = make_float4(cs0 + of0, cs1 + of1, cs2 + of2, cs3 + of3);
        }
    }
}

// ---------------------------------------------------------------------------
extern "C" void kernel_launch(void* const* d_in, const int* in_sizes, int n_in,
                              void* d_out, int out_size, void* d_ws, size_t ws_size,
                              hipStream_t stream) {
    (void)in_sizes; (void)n_in; (void)out_size; (void)ws_size;
    const float* bbox = (const float*)d_in[0];
    const float* head = (const float*)d_in[1];
    const float* c1w  = (const float*)d_in[2];
    const float* c1b  = (const float*)d_in[3];
    const float* c2w  = (const float*)d_in[4];
    const float* c2b  = (const float*)d_in[5];
    const float* fcw  = (const float*)d_in[6];
    const float* fcb  = (const float*)d_in[7];
    const float* ewih = (const float*)d_in[8];
    const float* ewhh = (const float*)d_in[9];
    const float* ebih = (const float*)d_in[10];
    const float* ebhh = (const float*)d_in[11];
    const float* dwih = (const float*)d_in[12];
    const float* dwhh = (const float*)d_in[13];
    const float* dbih = (const float*)d_in[14];
    const float* dbhh = (const float*)d_in[15];
    const float* linw = (const float*)d_in[16];
    const float* linb = (const float*)d_in[17];
    float* out = (float*)d_out;

    float* enc_in = (float*)d_ws;   // 1024*30*9 floats

    conv_embed_kernel<<<B_ * L_, 64, 0, stream>>>(bbox, head, c1w, c1b, c2w, c2b,
                                                  fcw, fcb, enc_in);
    gru_encdec_kernel<<<B_, 64, 0, stream>>>(bbox, enc_in,
                                             ewih, ewhh, ebih, ebhh,
                                             dwih, dwhh, dbih, dbhh,
                                             linw, linb, out);
}

// Round 10
// 284.527 us; speedup vs baseline: 1.8474x; 1.0379x over previous
//
#include <hip/hip_runtime.h>
#include <hip/hip_bf16.h>

// ---------------------------------------------------------------------------
// Split pipeline:
//   K1 conv_embed : R8 kernel (~88.6us, VALU-issue-bound).
//   K2 gru_mfma   : 64 blocks x 256 thr; 16 batch elements per block.
//     Recurrence via mfma_f32_16x16x32_f16: per step, gates [16 batch x 192]
//     = A(h|x, K=96 padded) x B(weights, reg-resident f16 frags).
//     One critical path serves 16 batches (R9 lesson: wall time = 50 steps x
//     path length; only path-shortening or batch-amortization helps).
//     Verified layouts (guide §3): A[m=lane&15][k=quad*8+j];
//     C/D col=lane&15 (N=unit), row=quad*4+reg (M=batch).
// ---------------------------------------------------------------------------

#define B_    1024
#define L_    30
#define H_    64

typedef _Float16 half_t;
typedef __attribute__((ext_vector_type(8))) _Float16 half8;
typedef __attribute__((ext_vector_type(4))) float f32x4;

#define MFMA16(A, B, C) __builtin_amdgcn_mfma_f32_16x16x32_f16(A, B, C, 0, 0, 0)

__device__ __forceinline__ float sigmoid_f(float v) {
    return __builtin_amdgcn_rcpf(1.f + __expf(-v));
}
__device__ __forceinline__ float tanh_f(float v) {
    v = fminf(fmaxf(v, -15.f), 15.f);
    const float e = __expf(2.f * v);
    return (e - 1.f) * __builtin_amdgcn_rcpf(e + 1.f);
}
__device__ __forceinline__ void load4_lds(float* r, const float* p) {
    float2 a = *(const float2*)p;
    float2 b = *(const float2*)(p + 2);
    r[0] = a.x; r[1] = a.y; r[2] = b.x; r[3] = b.y;
}

// ---------------------------------------------------------------------------
// Kernel A: per-image conv encoder + fc. One 64-thread block per image.
// (unchanged from R8/R9 — measured 88.6us, VALUBusy ~100%)
// ---------------------------------------------------------------------------
__global__ __launch_bounds__(64) void conv_embed_kernel(
    const float* __restrict__ bbox,
    const float* __restrict__ head,
    const float* __restrict__ c1w, const float* __restrict__ c1b,
    const float* __restrict__ c2w, const float* __restrict__ c2b,
    const float* __restrict__ fcw, const float* __restrict__ fcb,
    float* __restrict__ enc_in)
{
    const int img = blockIdx.x;          // 0..30719
    const int b = img / L_;
    const int l = img % L_;
    const int tid = threadIdx.x;

    __shared__ float s_img[32 * 32];
    __shared__ float s_p1[4 * 15 * 16];  // [c][py][px], width padded to 16
    __shared__ float s_p2[360];
    __shared__ float s_red[60];

    {
        const float4* src = (const float4*)(head + ((size_t)b * 31 + (size_t)l) * 1024);
        float4* dst = (float4*)s_img;
        #pragma unroll
        for (int i = 0; i < 4; ++i) dst[tid + 64 * i] = src[tid + 64 * i];
    }
    __syncthreads();

    if (tid < 60) {
        const int c = tid / 15, px = tid % 15;
        const int x0 = 2 * px;
        float wg[9];
        #pragma unroll
        for (int k = 0; k < 9; ++k) wg[k] = c1w[c * 9 + k];
        const float bias = c1b[c];

        auto c1out = [&](const float* ra, const float* rb, const float* rc, const float* rd) -> float {
            float a00 = bias, a01 = bias, a10 = bias, a11 = bias;
            #pragma unroll
            for (int kx = 0; kx < 3; ++kx) {
                const float w0 = wg[kx], w1 = wg[3 + kx], w2 = wg[6 + kx];
                a00 = fmaf(w0, ra[kx],     fmaf(w1, rb[kx],     fmaf(w2, rc[kx],     a00)));
                a01 = fmaf(w0, ra[kx + 1], fmaf(w1, rb[kx + 1], fmaf(w2, rc[kx + 1], a01)));
                a10 = fmaf(w0, rb[kx],     fmaf(w1, rc[kx],     fmaf(w2, rd[kx],     a10)));
                a11 = fmaf(w0, rb[kx + 1], fmaf(w1, rc[kx + 1], fmaf(w2, rd[kx + 1], a11)));
            }
            a00 = fmaxf(a00, 0.f); a01 = fmaxf(a01, 0.f);
            a10 = fmaxf(a10, 0.f); a11 = fmaxf(a11, 0.f);
            return fmaxf(fmaxf(a00, a01), fmaxf(a10, a11));
        };

        float r[6][4];
        load4_lds(r[0], s_img + 0 * 32 + x0);
        load4_lds(r[1], s_img + 1 * 32 + x0);
        #pragma unroll
        for (int i = 0; i < 7; ++i) {
            const int s0 = (4 * i) % 6, s1 = (4 * i + 1) % 6, s2 = (4 * i + 2) % 6;
            const int s3 = (4 * i + 3) % 6, s4 = (4 * i + 4) % 6, s5 = (4 * i + 5) % 6;
            load4_lds(r[s2], s_img + (4 * i + 2) * 32 + x0);
            load4_lds(r[s3], s_img + (4 * i + 3) * 32 + x0);
            s_p1[c * 240 + (2 * i) * 16 + px] = c1out(r[s0], r[s1], r[s2], r[s3]);
            load4_lds(r[s4], s_img + (4 * i + 4) * 32 + x0);
            load4_lds(r[s5], s_img + (4 * i + 5) * 32 + x0);
            s_p1[c * 240 + (2 * i + 1) * 16 + px] = c1out(r[s2], r[s3], r[s4], r[s5]);
        }
        load4_lds(r[0], s_img + 30 * 32 + x0);
        load4_lds(r[1], s_img + 31 * 32 + x0);
        s_p1[c * 240 + 14 * 16 + px] = c1out(r[4], r[5], r[0], r[1]);
    }
    __syncthreads();

    if (tid < 60) {
        const int c = tid / 6, px = tid % 6;
        const int x0 = 2 * px;
        float wg2[4][9];
        #pragma unroll
        for (int ic = 0; ic < 4; ++ic)
            #pragma unroll
            for (int k = 0; k < 9; ++k) wg2[ic][k] = c2w[(c * 4 + ic) * 9 + k];
        const float bias2 = c2b[c];

        float P[6][4][4];
        auto c2out = [&](float (*pa)[4], float (*pb)[4], float (*pc)[4], float (*pd)[4]) -> float {
            float a00 = bias2, a01 = bias2, a10 = bias2, a11 = bias2;
            #pragma unroll
            for (int ic = 0; ic < 4; ++ic) {
                #pragma unroll
                for (int kx = 0; kx < 3; ++kx) {
                    const float w0 = wg2[ic][kx], w1 = wg2[ic][3 + kx], w2 = wg2[ic][6 + kx];
                    a00 = fmaf(w0, pa[ic][kx],     fmaf(w1, pb[ic][kx],     fmaf(w2, pc[ic][kx],     a00)));
                    a01 = fmaf(w0, pa[ic][kx + 1], fmaf(w1, pb[ic][kx + 1], fmaf(w2, pc[ic][kx + 1], a01)));
                    a10 = fmaf(w0, pb[ic][kx],     fmaf(w1, pc[ic][kx],     fmaf(w2, pd[ic][kx],     a10)));
                    a11 = fmaf(w0, pb[ic][kx + 1], fmaf(w1, pc[ic][kx + 1], fmaf(w2, pd[ic][kx + 1], a11)));
                }
            }
            a00 = fmaxf(a00, 0.f); a01 = fmaxf(a01, 0.f);
            a10 = fmaxf(a10, 0.f); a11 = fmaxf(a11, 0.f);
            return fmaxf(fmaxf(a00, a01), fmaxf(a10, a11));
        };

        #pragma unroll
        for (int ic = 0; ic < 4; ++ic) {
            load4_lds(P[0][ic], s_p1 + ic * 240 + 0 * 16 + x0);
            load4_lds(P[1][ic], s_p1 + ic * 240 + 1 * 16 + x0);
        }
        #pragma unroll
        for (int i = 0; i < 3; ++i) {
            const int s0 = (4 * i) % 6, s1 = (4 * i + 1) % 6, s2 = (4 * i + 2) % 6;
            const int s3 = (4 * i + 3) % 6, s4 = (4 * i + 4) % 6, s5 = (4 * i + 5) % 6;
            #pragma unroll
            for (int ic = 0; ic < 4; ++ic) {
                load4_lds(P[s2][ic], s_p1 + ic * 240 + (4 * i + 2) * 16 + x0);
                load4_lds(P[s3][ic], s_p1 + ic * 240 + (4 * i + 3) * 16 + x0);
            }
            s_p2[c * 36 + (2 * i) * 6 + px] = c2out(P[s0], P[s1], P[s2], P[s3]);
            #pragma unroll
            for (int ic = 0; ic < 4; ++ic) {
                load4_lds(P[s4][ic], s_p1 + ic * 240 + (4 * i + 4) * 16 + x0);
                load4_lds(P[s5][ic], s_p1 + ic * 240 + (4 * i + 5) * 16 + x0);
            }
            s_p2[c * 36 + (2 * i + 1) * 6 + px] = c2out(P[s2], P[s3], P[s4], P[s5]);
        }
    }
    __syncthreads();

    if (tid < 60) {
        const int o = tid / 12, i0 = tid % 12;
        const float* wrow = fcw + o * 360;
        float acc = 0.f;
        #pragma unroll
        for (int k = 0; k < 30; ++k) {
            const int i = i0 + 12 * k;
            acc = fmaf(wrow[i], s_p2[i], acc);
        }
        s_red[tid] = acc;
    }
    __syncthreads();

    float* dst = enc_in + ((size_t)b * L_ + l) * 9;
    if (tid < 5) {
        float acc = fcb[tid];
        #pragma unroll
        for (int k = 0; k < 12; ++k) acc += s_red[tid * 12 + k];
        dst[4 + tid] = acc;
    } else if (tid >= 8 && tid < 12) {
        const int d = tid - 8;
        const float* bb = bbox + (size_t)b * 124 + (size_t)l * 4;
        dst[d] = bb[4 + d] - bb[d];
    }
}

// ---------------------------------------------------------------------------
// Kernel B: MFMA GRU enc+dec. 64 blocks x 256 threads, 16 batches/block.
// Wave w owns output units [16w..16w+16) for all 3 gates (tiles {w, w+4, w+8}
// in gate-major order). Weight B-frags register-resident (f16).
// ---------------------------------------------------------------------------
__global__ __launch_bounds__(256, 1) void gru_mfma_kernel(
    const float* __restrict__ bbox,     // [1024][31][4]
    const float* __restrict__ enc_in,   // [1024][30][9]
    const float* __restrict__ ewih, const float* __restrict__ ewhh,
    const float* __restrict__ ebih, const float* __restrict__ ebhh,
    const float* __restrict__ dwih, const float* __restrict__ dwhh,
    const float* __restrict__ dbih, const float* __restrict__ dbhh,
    const float* __restrict__ linw, const float* __restrict__ linb,
    float* __restrict__ out)            // [1024][20][4]
{
    const int bb  = blockIdx.x * 16;    // first batch of this block
    const int tid = threadIdx.x;
    const int w   = tid >> 6;           // wave 0..3
    const int l   = tid & 63;
    const int q   = l >> 4;             // quad 0..3
    const int col = l & 15;

    // hbuf rows padded 64->72 halves (+16B) so A-frag b128 reads spread banks.
    alignas(16) __shared__ half_t hbuf[2][16][72];   // [parity][batch][unit]
    alignas(16) __shared__ half_t xenc[30][16][40];  // [t][batch][k-64], cols 0..8 = x
    alignas(16) __shared__ half_t xdec[16][40];      // [batch][k-64], cols 0..3 = x

    // ---- zero LDS ----------------------------------------------------------
    {
        int4* p = (int4*)hbuf;
        for (int i = tid; i < (int)(sizeof(hbuf) / 16); i += 256) p[i] = int4{0, 0, 0, 0};
        p = (int4*)xenc;
        for (int i = tid; i < (int)(sizeof(xenc) / 16); i += 256) p[i] = int4{0, 0, 0, 0};
        p = (int4*)xdec;
        for (int i = tid; i < (int)(sizeof(xdec) / 16); i += 256) p[i] = int4{0, 0, 0, 0};
    }
    __syncthreads();

    // ---- stage encoder x into A-frag layout --------------------------------
    for (int pr = tid; pr < 480; pr += 256) {
        const int t = pr / 16, b = pr % 16;
        const float* src = enc_in + ((size_t)(bb + b) * L_ + t) * 9;
        #pragma unroll
        for (int d = 0; d < 9; ++d) xenc[t][b][d] = (half_t)src[d];
    }

    // ---- decoder x0 / offsets / cumsum (wave 0, col<4 lanes own (batch,d)) -
    float xold[4], ofs[4], cs[4];
    if (w == 0 && col < 4) {
        #pragma unroll
        for (int r = 0; r < 4; ++r) {
            const float* bbp = bbox + (size_t)(bb + q * 4 + r) * 124;
            xold[r] = bbp[120 + col] - bbp[116 + col];
            ofs[r]  = bbp[120 + col];
            cs[r]   = 0.f;
            xdec[q * 4 + r][col] = (half_t)xold[r];
        }
    }

    // ---- weight B-fragments (register-resident, f16) -----------------------
    // B[k][n] = W[n_global][k];  lane holds k = kap*32 + q*8 + j, n_global =
    // gate*64 + 16w + col  ->  8 consecutive elements of row n_global.
    const int urow = 16 * w + col;
    auto whh_frag = [&](const float* W, int gate, int kap) -> half8 {
        const float* rp = W + (size_t)(gate * 64 + urow) * 64 + kap * 32 + q * 8;
        half8 f;
        #pragma unroll
        for (int j = 0; j < 8; ++j) f[j] = (half_t)rp[j];
        return f;
    };
    auto wih_frag = [&](const float* W, int gate, int indim) -> half8 {
        half8 f;
        #pragma unroll
        for (int j = 0; j < 8; ++j) {
            const int d = q * 8 + j;
            f[j] = (d < indim) ? (half_t)W[(size_t)(gate * 64 + urow) * indim + d]
                               : (half_t)0.f;
        }
        return f;
    };

    const half8 eBr0 = whh_frag(ewhh, 0, 0), eBr1 = whh_frag(ewhh, 0, 1);
    const half8 eBz0 = whh_frag(ewhh, 1, 0), eBz1 = whh_frag(ewhh, 1, 1);
    const half8 eBn0 = whh_frag(ewhh, 2, 0), eBn1 = whh_frag(ewhh, 2, 1);
    const half8 eBrx = wih_frag(ewih, 0, 9);
    const half8 eBzx = wih_frag(ewih, 1, 9);
    const half8 eBnx = wih_frag(ewih, 2, 9);

    const half8 dBr0 = whh_frag(dwhh, 0, 0), dBr1 = whh_frag(dwhh, 0, 1);
    const half8 dBz0 = whh_frag(dwhh, 1, 0), dBz1 = whh_frag(dwhh, 1, 1);
    const half8 dBn0 = whh_frag(dwhh, 2, 0), dBn1 = whh_frag(dwhh, 2, 1);
    const half8 dBrx = wih_frag(dwih, 0, 4);
    const half8 dBzx = wih_frag(dwih, 1, 4);
    const half8 dBnx = wih_frag(dwih, 2, 4);

    half8 Bl0, Bl1;   // lin head: B[k][n] = linw[n][k], n = col (<4)
    #pragma unroll
    for (int j = 0; j < 8; ++j) {
        Bl0[j] = (col < 4) ? (half_t)linw[col * 64 +      q * 8 + j] : (half_t)0.f;
        Bl1[j] = (col < 4) ? (half_t)linw[col * 64 + 32 + q * 8 + j] : (half_t)0.f;
    }

    // biases for this lane's unit (same for all 4 batch regs)
    const float ebr  = ebih[urow]       + ebhh[urow];
    const float ebz  = ebih[64 + urow]  + ebhh[64 + urow];
    const float ebnh = ebhh[128 + urow];
    const float ebni = ebih[128 + urow];
    const float dbr  = dbih[urow]       + dbhh[urow];
    const float dbz  = dbih[64 + urow]  + dbhh[64 + urow];
    const float dbnh = dbhh[128 + urow];
    const float dbni = dbih[128 + urow];
    const float lb   = (col < 4) ? linb[col] : 0.f;

    float hold[4] = {0.f, 0.f, 0.f, 0.f};  // h for (batch q*4+r, unit urow)
    __syncthreads();

    // =================== encoder: 30 steps =================================
    for (int t = 0; t < L_; ++t) {
        const int p = t & 1;
        const half8 a0 = *(const half8*)&hbuf[p][col][q * 8];        // k 0..31
        const half8 a1 = *(const half8*)&hbuf[p][col][32 + q * 8];   // k 32..63
        const half8 a2 = *(const half8*)&xenc[t][col][q * 8];        // k 64..95

        f32x4 Cr  = {ebr, ebr, ebr, ebr};
        f32x4 Cz  = {ebz, ebz, ebz, ebz};
        f32x4 Cnh = {ebnh, ebnh, ebnh, ebnh};
        f32x4 Cnx = {ebni, ebni, ebni, ebni};
        Cr  = MFMA16(a0, eBr0, Cr);  Cr  = MFMA16(a1, eBr1, Cr);  Cr = MFMA16(a2, eBrx, Cr);
        Cz  = MFMA16(a0, eBz0, Cz);  Cz  = MFMA16(a1, eBz1, Cz);  Cz = MFMA16(a2, eBzx, Cz);
        Cnh = MFMA16(a0, eBn0, Cnh); Cnh = MFMA16(a1, eBn1, Cnh);
        Cnx = MFMA16(a2, eBnx, Cnx);

        #pragma unroll
        for (int r = 0; r < 4; ++r) {
            const float rr = sigmoid_f(Cr[r]);
            const float zz = sigmoid_f(Cz[r]);
            const float nn = tanh_f(Cnx[r] + rr * Cnh[r]);
            hold[r] = fmaf(zz, hold[r] - nn, nn);
            hbuf[p ^ 1][q * 4 + r][urow] = (half_t)hold[r];
        }
        __syncthreads();
    }

    // =================== decoder: 20 steps + lin + cumsum ==================
    for (int tt = 0; tt < 20; ++tt) {
        const int p = tt & 1;   // (30+tt)&1 == tt&1
        const half8 a0 = *(const half8*)&hbuf[p][col][q * 8];
        const half8 a1 = *(const half8*)&hbuf[p][col][32 + q * 8];
        const half8 a2 = *(const half8*)&xdec[col][q * 8];

        f32x4 Cr  = {dbr, dbr, dbr, dbr};
        f32x4 Cz  = {dbz, dbz, dbz, dbz};
        f32x4 Cnh = {dbnh, dbnh, dbnh, dbnh};
        f32x4 Cnx = {dbni, dbni, dbni, dbni};
        Cr  = MFMA16(a0, dBr0, Cr);  Cr  = MFMA16(a1, dBr1, Cr);  Cr = MFMA16(a2, dBrx, Cr);
        Cz  = MFMA16(a0, dBz0, Cz);  Cz  = MFMA16(a1, dBz1, Cz);  Cz = MFMA16(a2, dBzx, Cz);
        Cnh = MFMA16(a0, dBn0, Cnh); Cnh = MFMA16(a1, dBn1, Cnh);
        Cnx = MFMA16(a2, dBnx, Cnx);

        #pragma unroll
        for (int r = 0; r < 4; ++r) {
            const float rr = sigmoid_f(Cr[r]);
            const float zz = sigmoid_f(Cz[r]);
            const float nn = tanh_f(Cnx[r] + rr * Cnh[r]);
            hold[r] = fmaf(zz, hold[r] - nn, nn);
            hbuf[p ^ 1][q * 4 + r][urow] = (half_t)hold[r];
        }
        __syncthreads();   // (A) h_new visible for lin-head A-frags

        // lin head: X[batch][d] = h_new . linw[d]   (all waves redundant)
        const half8 al0 = *(const half8*)&hbuf[p ^ 1][col][q * 8];
        const half8 al1 = *(const half8*)&hbuf[p ^ 1][col][32 + q * 8];
        f32x4 X = {0.f, 0.f, 0.f, 0.f};
        X = MFMA16(al0, Bl0, X);
        X = MFMA16(al1, Bl1, X);

        if (w == 0 && col < 4) {
            #pragma unroll
            for (int r = 0; r < 4; ++r) {
                const float xv = X[r] + lb + xold[r];
                xold[r] = xv;
                cs[r] += xv;
                xdec[q * 4 + r][col] = (half_t)xv;
                out[(size_t)(bb + q * 4 + r) * 80 + tt * 4 + col] = cs[r] + ofs[r];
            }
        }
        __syncthreads();   // (B) xdec visible for next step's gi
    }
}

// ---------------------------------------------------------------------------
extern "C" void kernel_launch(void* const* d_in, const int* in_sizes, int n_in,
                              void* d_out, int out_size, void* d_ws, size_t ws_size,
                              hipStream_t stream) {
    (void)in_sizes; (void)n_in; (void)out_size; (void)ws_size;
    const float* bbox = (const float*)d_in[0];
    const float* head = (const float*)d_in[1];
    const float* c1w  = (const float*)d_in[2];
    const float* c1b  = (const float*)d_in[3];
    const float* c2w  = (const float*)d_in[4];
    const float* c2b  = (const float*)d_in[5];
    const float* fcw  = (const float*)d_in[6];
    const float* fcb  = (const float*)d_in[7];
    const float* ewih = (const float*)d_in[8];
    const float* ewhh = (const float*)d_in[9];
    const float* ebih = (const float*)d_in[10];
    const float* ebhh = (const float*)d_in[11];
    const float* dwih = (const float*)d_in[12];
    const float* dwhh = (const float*)d_in[13];
    const float* dbih = (const float*)d_in[14];
    const float* dbhh = (const float*)d_in[15];
    const float* linw = (const float*)d_in[16];
    const float* linb = (const float*)d_in[17];
    float* out = (float*)d_out;

    float* enc_in = (float*)d_ws;   // 1024*30*9 floats

    conv_embed_kernel<<<B_ * L_, 64, 0, stream>>>(bbox, head, c1w, c1b, c2w, c2b,
                                                  fcw, fcb, enc_in);
    gru_mfma_kernel<<<B_ / 16, 256, 0, stream>>>(bbox, enc_in,
                                                 ewih, ewhh, ebih, ebhh,
                                                 dwih, dwhh, dbih, dbhh,
                                                 linw, linb, out);
}